// Round 1
// baseline (2291.249 us; speedup 1.0000x reference)
//
#include <hip/hip_runtime.h>
#include <hip/hip_bf16.h>

// ---------------- CSR build ----------------

__global__ void count_kernel(const int* __restrict__ dst, int* __restrict__ deg, int E) {
    int e = blockIdx.x * blockDim.x + threadIdx.x;
    if (e < E) atomicAdd(&deg[dst[e]], 1);
}

__global__ void dinv_kernel(const int* __restrict__ deg, float* __restrict__ dinv, int n) {
    int v = blockIdx.x * blockDim.x + threadIdx.x;
    if (v < n) dinv[v] = rsqrtf((float)(deg[v] + 1));   // +1 self loop
}

#define SC_T 256
#define SC_C 1024

__global__ void scan_part(const int* __restrict__ deg, int* __restrict__ bsum, int n) {
    __shared__ int sh[SC_T];
    int t = threadIdx.x;
    int base = blockIdx.x * SC_C;
    int s = 0;
    for (int i = 0; i < 4; i++) {
        int idx = base + t * 4 + i;
        if (idx < n) s += deg[idx];
    }
    sh[t] = s;
    __syncthreads();
    for (int off = 128; off > 0; off >>= 1) {
        if (t < off) sh[t] += sh[t + off];
        __syncthreads();
    }
    if (t == 0) bsum[blockIdx.x] = sh[0];
}

__global__ void scan_bsums(int* bsum, int nb, int* total) {
    if (threadIdx.x == 0 && blockIdx.x == 0) {
        int acc = 0;
        for (int i = 0; i < nb; i++) { int v = bsum[i]; bsum[i] = acc; acc += v; }
        *total = acc;
    }
}

__global__ void scan_write(const int* __restrict__ deg, const int* __restrict__ bsum,
                           const int* __restrict__ total, int* __restrict__ rp, int n) {
    __shared__ int sh[SC_T];
    int t = threadIdx.x;
    int base = blockIdx.x * SC_C;
    int vals[4];
    int s = 0;
    for (int i = 0; i < 4; i++) {
        int idx = base + t * 4 + i;
        vals[i] = (idx < n) ? deg[idx] : 0;
        s += vals[i];
    }
    sh[t] = s;
    __syncthreads();
    // inclusive Hillis-Steele scan over thread sums
    for (int off = 1; off < SC_T; off <<= 1) {
        int v = (t >= off) ? sh[t - off] : 0;
        __syncthreads();
        sh[t] += v;
        __syncthreads();
    }
    int excl = sh[t] - s + bsum[blockIdx.x];
    for (int i = 0; i < 4; i++) {
        int idx = base + t * 4 + i;
        if (idx < n) { rp[idx] = excl; excl += vals[i]; }
    }
    if (blockIdx.x == 0 && t == 0) rp[n] = *total;
}

__global__ void fill_adj(const int* __restrict__ src, const int* __restrict__ dst,
                         const int* __restrict__ rp, int* __restrict__ cursor,
                         int* __restrict__ adj, int E) {
    int e = blockIdx.x * blockDim.x + threadIdx.x;
    if (e < E) {
        int d = dst[e];
        int p = atomicAdd(&cursor[d], 1);
        adj[rp[d] + p] = src[e];
    }
}

// ---------------- GEMM: C[M,128] = A[M,K] @ W[K,128], fp32 ----------------

__global__ __launch_bounds__(256) void gemm_f32_128(
        const float* __restrict__ A, const float* __restrict__ W,
        float* __restrict__ C, int M, int K) {
    __shared__ float As[64][17];
    __shared__ float Wsh[16][128];
    int t = threadIdx.x;
    int brow = blockIdx.x * 64;
    int cg = t & 31;   // cols cg*4 .. cg*4+3
    int rg = t >> 5;   // rows rg*8 .. rg*8+7
    float acc[8][4] = {};
    for (int k0 = 0; k0 < K; k0 += 16) {
        for (int i = t; i < 64 * 16; i += 256) {
            int r = i >> 4, kk = i & 15;
            int gr = brow + r;
            As[r][kk] = (gr < M) ? A[(size_t)gr * K + k0 + kk] : 0.f;
        }
        for (int i = t; i < 16 * 128; i += 256) {
            int kk = i >> 7, c = i & 127;
            Wsh[kk][c] = W[(size_t)(k0 + kk) * 128 + c];
        }
        __syncthreads();
#pragma unroll
        for (int kk = 0; kk < 16; ++kk) {
            float4 wv = *(const float4*)&Wsh[kk][cg * 4];
#pragma unroll
            for (int rr = 0; rr < 8; ++rr) {
                float av = As[rg * 8 + rr][kk];
                acc[rr][0] += av * wv.x;
                acc[rr][1] += av * wv.y;
                acc[rr][2] += av * wv.z;
                acc[rr][3] += av * wv.w;
            }
        }
        __syncthreads();
    }
    for (int rr = 0; rr < 8; ++rr) {
        int gr = brow + rg * 8 + rr;
        if (gr < M)
            *(float4*)&C[(size_t)gr * 128 + cg * 4] =
                make_float4(acc[rr][0], acc[rr][1], acc[rr][2], acc[rr][3]);
    }
}

// ---------------- propagation: out[v] = dinv[v]*(sum_in dinv[u]*A[idx(u)] + dinv[v]*A[idx(v)]) + b ----------------

template <bool PERM, bool RELU>
__global__ __launch_bounds__(256) void prop_kernel(
        const float* __restrict__ A, const int* __restrict__ rp,
        const int* __restrict__ adj, const float* __restrict__ dinv,
        const int* __restrict__ perm, const float* __restrict__ bias,
        float* __restrict__ out, int n) {
    int wid = (blockIdx.x * blockDim.x + threadIdx.x) >> 6;
    if (wid >= n) return;
    int lane = threadIdx.x & 63;
    int v = wid;
    float dv = dinv[v];
    int self = PERM ? perm[v] : v;
    float acc0 = A[(size_t)self * 128 + lane] * dv;
    float acc1 = A[(size_t)self * 128 + 64 + lane] * dv;
    int beg = rp[v], end = rp[v + 1];
    for (int i = beg; i < end; ++i) {
        int u = adj[i];
        float du = dinv[u];
        int uu = PERM ? perm[u] : u;
        acc0 += A[(size_t)uu * 128 + lane] * du;
        acc1 += A[(size_t)uu * 128 + 64 + lane] * du;
    }
    acc0 = acc0 * dv + bias[lane];
    acc1 = acc1 * dv + bias[64 + lane];
    if (RELU) { acc0 = fmaxf(acc0, 0.f); acc1 = fmaxf(acc1, 0.f); }
    out[(size_t)v * 128 + lane] = acc0;
    out[(size_t)v * 128 + 64 + lane] = acc1;
}

// ---------------- readout ----------------

__global__ void colsum_kernel(const float* __restrict__ H, float* __restrict__ colsum, int n) {
    int t = threadIdx.x;  // 128
    int r0 = blockIdx.x * 512;
    int r1 = min(r0 + 512, n);
    float acc = 0.f;
    for (int r = r0; r < r1; ++r) acc += H[(size_t)r * 128 + t];
    atomicAdd(&colsum[t], acc);
}

__global__ void sws_kernel(const float* __restrict__ colsum, const float* __restrict__ Wd,
                           float* __restrict__ Ws, int n) {
    __shared__ float s_sh[128];
    int t = threadIdx.x;  // 128
    float m = colsum[t] / (float)n;
    s_sh[t] = 1.f / (1.f + expf(-m));
    __syncthreads();
    float acc = 0.f;
    for (int j = 0; j < 128; ++j) acc += Wd[t * 128 + j] * s_sh[j];
    Ws[t] = acc;
}

__global__ __launch_bounds__(256) void final_kernel(
        const float* __restrict__ H, const float* __restrict__ Hc,
        const float* __restrict__ Ws, const float* __restrict__ bd,
        float* __restrict__ out, int n) {
    int wid = (blockIdx.x * blockDim.x + threadIdx.x) >> 6;
    if (wid >= n) return;
    int lane = threadIdx.x & 63;
    float w0 = Ws[lane], w1 = Ws[64 + lane];
    float a = H[(size_t)wid * 128 + lane] * w0 + H[(size_t)wid * 128 + 64 + lane] * w1;
    float b = Hc[(size_t)wid * 128 + lane] * w0 + Hc[(size_t)wid * 128 + 64 + lane] * w1;
    for (int off = 32; off > 0; off >>= 1) {
        a += __shfl_xor(a, off);
        b += __shfl_xor(b, off);
    }
    if (lane == 0) {
        out[wid] = a + bd[0];
        out[n + wid] = b + bd[0];
    }
}

// ---------------- launch ----------------

extern "C" void kernel_launch(void* const* d_in, const int* in_sizes, int n_in,
                              void* d_out, int out_size, void* d_ws, size_t ws_size,
                              hipStream_t stream) {
    const float* x  = (const float*)d_in[0];
    const int*   ei = (const int*)d_in[1];
    const int* perm = (const int*)d_in[2];
    const float* W1 = (const float*)d_in[3];
    const float* b1 = (const float*)d_in[4];
    const float* W2 = (const float*)d_in[5];
    const float* b2 = (const float*)d_in[6];
    const float* Wd = (const float*)d_in[7];
    const float* bd = (const float*)d_in[8];

    const int N = in_sizes[2];
    const int E = in_sizes[1] / 2;
    const int IN = in_sizes[0] / N;  // 512
    const int* src = ei;
    const int* dst = ei + E;
    float* out = (float*)d_out;

    // workspace carve (512B aligned)
    char* p = (char*)d_ws;
    auto alloc = [&](size_t bytes) -> void* {
        void* r = (void*)p;
        p += (bytes + 511) & ~(size_t)511;
        return r;
    };
    int*   deg_i  = (int*)alloc((size_t)N * 4);
    int*   cursor = (int*)alloc((size_t)N * 4);
    int*   rp     = (int*)alloc((size_t)(N + 1) * 4);
    int*   adj    = (int*)alloc((size_t)E * 4);
    float* dinv   = (float*)alloc((size_t)N * 4);
    int*   bsum   = (int*)alloc(4096);
    int*   total  = (int*)alloc(64);
    float* colsum = (float*)alloc(512);
    float* Wsv    = (float*)alloc(512);
    float* A = (float*)alloc((size_t)N * 128 * 4);  // XW1
    float* B = (float*)alloc((size_t)N * 128 * 4);  // h1 / h1c / Hc
    float* C = (float*)alloc((size_t)N * 128 * 4);  // h1@W2
    float* D = (float*)alloc((size_t)N * 128 * 4);  // H

    hipMemsetAsync(deg_i, 0, (size_t)N * 4, stream);
    hipMemsetAsync(cursor, 0, (size_t)N * 4, stream);
    hipMemsetAsync(colsum, 0, 512, stream);

    count_kernel<<<(E + 255) / 256, 256, 0, stream>>>(dst, deg_i, E);
    dinv_kernel<<<(N + 255) / 256, 256, 0, stream>>>(deg_i, dinv, N);

    int nb = (N + SC_C - 1) / SC_C;
    scan_part<<<nb, SC_T, 0, stream>>>(deg_i, bsum, N);
    scan_bsums<<<1, 1, 0, stream>>>(bsum, nb, total);
    scan_write<<<nb, SC_T, 0, stream>>>(deg_i, bsum, total, rp, N);
    fill_adj<<<(E + 255) / 256, 256, 0, stream>>>(src, dst, rp, cursor, adj, E);

    int gemm_blocks = (N + 63) / 64;
    int prop_blocks = (N + 3) / 4;

    // normal branch
    gemm_f32_128<<<gemm_blocks, 256, 0, stream>>>(x, W1, A, N, IN);
    prop_kernel<false, true><<<prop_blocks, 256, 0, stream>>>(A, rp, adj, dinv, perm, b1, B, N);
    gemm_f32_128<<<gemm_blocks, 256, 0, stream>>>(B, W2, C, N, 128);
    prop_kernel<false, false><<<prop_blocks, 256, 0, stream>>>(C, rp, adj, dinv, perm, b2, D, N);

    // corrupted branch (x[perm] @ W1 == A[perm])
    prop_kernel<true, true><<<prop_blocks, 256, 0, stream>>>(A, rp, adj, dinv, perm, b1, B, N);
    gemm_f32_128<<<gemm_blocks, 256, 0, stream>>>(B, W2, C, N, 128);
    prop_kernel<false, false><<<prop_blocks, 256, 0, stream>>>(C, rp, adj, dinv, perm, b2, B, N);  // Hc -> B

    // readout
    colsum_kernel<<<(N + 511) / 512, 128, 0, stream>>>(D, colsum, N);
    sws_kernel<<<1, 128, 0, stream>>>(colsum, Wd, Wsv, N);
    final_kernel<<<prop_blocks, 256, 0, stream>>>(D, B, Wsv, bd, out, N);
}

// Round 2
// 1063.264 us; speedup vs baseline: 2.1549x; 2.1549x over previous
//
#include <hip/hip_runtime.h>
#include <hip/hip_bf16.h>

typedef unsigned int uint;
typedef unsigned short ushort;
typedef __attribute__((ext_vector_type(8))) short bf16x8;
typedef __attribute__((ext_vector_type(4))) float f32x4;

static __device__ __forceinline__ ushort f2bf(float f) {
    uint u = __builtin_bit_cast(uint, f);
    uint r = (u + 0x7FFFu + ((u >> 16) & 1u)) >> 16;
    return (ushort)r;
}
static __device__ __forceinline__ float bflo(uint u) { return __builtin_bit_cast(float, u << 16); }
static __device__ __forceinline__ float bfhi(uint u) { return __builtin_bit_cast(float, u & 0xFFFF0000u); }

// ---------------- CSR build ----------------

__global__ void count_kernel(const int* __restrict__ dst, int* __restrict__ deg, int E) {
    int e = blockIdx.x * blockDim.x + threadIdx.x;
    if (e < E) atomicAdd(&deg[dst[e]], 1);
}

__global__ void dinv_kernel(const int* __restrict__ deg, float* __restrict__ dinv, int n) {
    int v = blockIdx.x * blockDim.x + threadIdx.x;
    if (v < n) dinv[v] = rsqrtf((float)(deg[v] + 1));
}

#define SC_T 256
#define SC_C 1024

__global__ void scan_part(const int* __restrict__ deg, int* __restrict__ bsum, int n) {
    __shared__ int sh[SC_T];
    int t = threadIdx.x;
    int base = blockIdx.x * SC_C;
    int s = 0;
    for (int i = 0; i < 4; i++) {
        int idx = base + t * 4 + i;
        if (idx < n) s += deg[idx];
    }
    sh[t] = s;
    __syncthreads();
    for (int off = 128; off > 0; off >>= 1) {
        if (t < off) sh[t] += sh[t + off];
        __syncthreads();
    }
    if (t == 0) bsum[blockIdx.x] = sh[0];
}

__global__ void scan_bsums(int* bsum, int nb, int* total) {
    if (threadIdx.x == 0 && blockIdx.x == 0) {
        int acc = 0;
        for (int i = 0; i < nb; i++) { int v = bsum[i]; bsum[i] = acc; acc += v; }
        *total = acc;
    }
}

__global__ void scan_write(const int* __restrict__ deg, const int* __restrict__ bsum,
                           const int* __restrict__ total, int* __restrict__ rp, int n) {
    __shared__ int sh[SC_T];
    int t = threadIdx.x;
    int base = blockIdx.x * SC_C;
    int vals[4];
    int s = 0;
    for (int i = 0; i < 4; i++) {
        int idx = base + t * 4 + i;
        vals[i] = (idx < n) ? deg[idx] : 0;
        s += vals[i];
    }
    sh[t] = s;
    __syncthreads();
    for (int off = 1; off < SC_T; off <<= 1) {
        int v = (t >= off) ? sh[t - off] : 0;
        __syncthreads();
        sh[t] += v;
        __syncthreads();
    }
    int excl = sh[t] - s + bsum[blockIdx.x];
    for (int i = 0; i < 4; i++) {
        int idx = base + t * 4 + i;
        if (idx < n) { rp[idx] = excl; excl += vals[i]; }
    }
    if (blockIdx.x == 0 && t == 0) rp[n] = *total;
}

__global__ void fill_adj(const int* __restrict__ src, const int* __restrict__ dst,
                         const int* __restrict__ rp, int* __restrict__ cursor,
                         int* __restrict__ adj, int E) {
    int e = blockIdx.x * blockDim.x + threadIdx.x;
    if (e < E) {
        int d = dst[e];
        int p = atomicAdd(&cursor[d], 1);
        adj[rp[d] + p] = src[e];
    }
}

// ---------------- W pre-pack into MFMA B-fragment layout ----------------
// Wp[((kc*8 + n)*64 + lane)*8 + j] = W[kc*32 + (lane>>4)*8 + j][n*16 + (lane&15)]

__global__ void pack_w(const float* __restrict__ W, ushort* __restrict__ Wp) {
    int kc = blockIdx.x >> 3, n = blockIdx.x & 7;
    int l = threadIdx.x;
    ushort o[8];
#pragma unroll
    for (int j = 0; j < 8; ++j) {
        float v = W[(size_t)(kc * 32 + ((l >> 4) * 8) + j) * 128 + n * 16 + (l & 15)];
        o[j] = f2bf(v);
    }
    uint4 pk;
    pk.x = (uint)o[0] | ((uint)o[1] << 16);
    pk.y = (uint)o[2] | ((uint)o[3] << 16);
    pk.z = (uint)o[4] | ((uint)o[5] << 16);
    pk.w = (uint)o[6] | ((uint)o[7] << 16);
    *(uint4*)(Wp + ((size_t)(kc * 8 + n) * 64 + l) * 8) = pk;
}

// ---------------- GEMM1: Cb[M,128](bf16) = X[M,K](fp32) @ W1 (packed) ----------------

__global__ __launch_bounds__(256) void gemm1_mfma(
        const float* __restrict__ X, const ushort* __restrict__ Wp,
        ushort* __restrict__ Cb, int M, int K) {
    __shared__ ushort As[64][40];   // 80B rows, 16B aligned
    int t = threadIdx.x, lane = t & 63, w = t >> 6;
    int brow = blockIdx.x * 64;
    int KC = K >> 5;
    f32x4 acc[8] = {};
    int sr = t >> 2, sk = (t & 3) * 8;          // staging: row, k-offset
    int gr = brow + sr;
    int frow = w * 16 + (lane & 15);            // fragment row within tile
    int fk = (lane >> 4) * 8;
    for (int kc = 0; kc < KC; ++kc) {
        float4 xa = make_float4(0.f, 0.f, 0.f, 0.f), xb = xa;
        if (gr < M) {
            const float* xp = X + (size_t)gr * K + kc * 32 + sk;
            xa = *(const float4*)xp;
            xb = *(const float4*)(xp + 4);
        }
        uint4 pk;
        pk.x = (uint)f2bf(xa.x) | ((uint)f2bf(xa.y) << 16);
        pk.y = (uint)f2bf(xa.z) | ((uint)f2bf(xa.w) << 16);
        pk.z = (uint)f2bf(xb.x) | ((uint)f2bf(xb.y) << 16);
        pk.w = (uint)f2bf(xb.z) | ((uint)f2bf(xb.w) << 16);
        __syncthreads();
        *(uint4*)&As[sr][sk] = pk;
        __syncthreads();
        bf16x8 af = *(const bf16x8*)&As[frow][fk];
        const ushort* wbase = Wp + ((size_t)(kc * 8) * 64 + lane) * 8;
#pragma unroll
        for (int n = 0; n < 8; ++n) {
            bf16x8 bfr = *(const bf16x8*)(wbase + (size_t)n * 64 * 8);
            acc[n] = __builtin_amdgcn_mfma_f32_16x16x32_bf16(af, bfr, acc[n], 0, 0, 0);
        }
    }
    int colbase = lane & 15;
    int rowbase = brow + w * 16 + ((lane >> 4) << 2);
#pragma unroll
    for (int n = 0; n < 8; ++n) {
#pragma unroll
        for (int r = 0; r < 4; ++r) {
            int grr = rowbase + r;
            if (grr < M) Cb[(size_t)grr * 128 + n * 16 + colbase] = f2bf(acc[n][r]);
        }
    }
}

// ---------------- GEMM2: Cb[M,128](bf16) = Ab[M,128](bf16) @ W (packed), K=128 ----------------

__global__ __launch_bounds__(256) void gemm2_mfma(
        const ushort* __restrict__ Ab, const ushort* __restrict__ Wp,
        ushort* __restrict__ Cb, int M) {
    int t = threadIdx.x, lane = t & 63, w = t >> 6;
    int brow = blockIdx.x * 64;
    int row16 = brow + w * 16 + (lane & 15);
    int fk = (lane >> 4) * 8;
    f32x4 acc[8] = {};
#pragma unroll
    for (int kc = 0; kc < 4; ++kc) {
        bf16x8 af = {};
        if (row16 < M) af = *(const bf16x8*)(Ab + (size_t)row16 * 128 + kc * 32 + fk);
        const ushort* wbase = Wp + ((size_t)(kc * 8) * 64 + lane) * 8;
#pragma unroll
        for (int n = 0; n < 8; ++n) {
            bf16x8 bfr = *(const bf16x8*)(wbase + (size_t)n * 64 * 8);
            acc[n] = __builtin_amdgcn_mfma_f32_16x16x32_bf16(af, bfr, acc[n], 0, 0, 0);
        }
    }
    int colbase = lane & 15;
    int rowbase = brow + w * 16 + ((lane >> 4) << 2);
#pragma unroll
    for (int n = 0; n < 8; ++n) {
#pragma unroll
        for (int r = 0; r < 4; ++r) {
            int grr = rowbase + r;
            if (grr < M) Cb[(size_t)grr * 128 + n * 16 + colbase] = f2bf(acc[n][r]);
        }
    }
}

// ---------------- fused dual propagation ----------------
// MODE 0: P1 indexed through perm (layer 1, P0==P1==A). MODE 1: two matrices, same index.

template <int MODE, bool RELU, typename OT>
__global__ __launch_bounds__(256) void prop2x(
        const ushort* __restrict__ P0, const ushort* __restrict__ P1,
        const int* __restrict__ rp, const int* __restrict__ adj,
        const float* __restrict__ dinv, const int* __restrict__ perm,
        const float* __restrict__ bias, OT* __restrict__ O0, OT* __restrict__ O1, int n) {
    int wid = (blockIdx.x * blockDim.x + threadIdx.x) >> 6;
    if (wid >= n) return;
    int lane = threadIdx.x & 63;
    float dv = dinv[wid];
    int s1 = (MODE == 0) ? perm[wid] : wid;
    uint r0 = *(const uint*)(P0 + (size_t)wid * 128 + 2 * lane);
    uint r1 = *(const uint*)(P1 + (size_t)s1 * 128 + 2 * lane);
    float a0x = bflo(r0) * dv, a0y = bfhi(r0) * dv;
    float a1x = bflo(r1) * dv, a1y = bfhi(r1) * dv;
    int i = rp[wid], end = rp[wid + 1];
    while (i + 8 <= end) {
        int us[8]; float du[8]; int u1s[8]; uint v0[8], v1[8];
#pragma unroll
        for (int k = 0; k < 8; ++k) us[k] = adj[i + k];
#pragma unroll
        for (int k = 0; k < 8; ++k) {
            du[k] = dinv[us[k]];
            u1s[k] = (MODE == 0) ? perm[us[k]] : us[k];
        }
#pragma unroll
        for (int k = 0; k < 8; ++k) v0[k] = *(const uint*)(P0 + (size_t)us[k] * 128 + 2 * lane);
#pragma unroll
        for (int k = 0; k < 8; ++k) v1[k] = *(const uint*)(P1 + (size_t)u1s[k] * 128 + 2 * lane);
#pragma unroll
        for (int k = 0; k < 8; ++k) {
            a0x += bflo(v0[k]) * du[k]; a0y += bfhi(v0[k]) * du[k];
            a1x += bflo(v1[k]) * du[k]; a1y += bfhi(v1[k]) * du[k];
        }
        i += 8;
    }
    for (; i < end; ++i) {
        int u = adj[i];
        float du = dinv[u];
        int uu = (MODE == 0) ? perm[u] : u;
        uint v0 = *(const uint*)(P0 + (size_t)u * 128 + 2 * lane);
        uint v1 = *(const uint*)(P1 + (size_t)uu * 128 + 2 * lane);
        a0x += bflo(v0) * du; a0y += bfhi(v0) * du;
        a1x += bflo(v1) * du; a1y += bfhi(v1) * du;
    }
    float2 bb = *(const float2*)(bias + 2 * lane);
    a0x = a0x * dv + bb.x; a0y = a0y * dv + bb.y;
    a1x = a1x * dv + bb.x; a1y = a1y * dv + bb.y;
    if (RELU) {
        a0x = fmaxf(a0x, 0.f); a0y = fmaxf(a0y, 0.f);
        a1x = fmaxf(a1x, 0.f); a1y = fmaxf(a1y, 0.f);
    }
    if constexpr (sizeof(OT) == 2) {
        *(uint*)(O0 + (size_t)wid * 128 + 2 * lane) = (uint)f2bf(a0x) | ((uint)f2bf(a0y) << 16);
        *(uint*)(O1 + (size_t)wid * 128 + 2 * lane) = (uint)f2bf(a1x) | ((uint)f2bf(a1y) << 16);
    } else {
        *(float2*)(O0 + (size_t)wid * 128 + 2 * lane) = make_float2(a0x, a0y);
        *(float2*)(O1 + (size_t)wid * 128 + 2 * lane) = make_float2(a1x, a1y);
    }
}

// ---------------- readout ----------------

__global__ void colsum_kernel(const float* __restrict__ H, float* __restrict__ colsum, int n) {
    int t = threadIdx.x;  // 128
    int r0 = blockIdx.x * 512;
    int r1 = min(r0 + 512, n);
    float acc = 0.f;
    for (int r = r0; r < r1; ++r) acc += H[(size_t)r * 128 + t];
    atomicAdd(&colsum[t], acc);
}

__global__ void sws_kernel(const float* __restrict__ colsum, const float* __restrict__ Wd,
                           float* __restrict__ Ws, int n) {
    __shared__ float s_sh[128];
    int t = threadIdx.x;  // 128
    float m = colsum[t] / (float)n;
    s_sh[t] = 1.f / (1.f + expf(-m));
    __syncthreads();
    float acc = 0.f;
    for (int j = 0; j < 128; ++j) acc += Wd[t * 128 + j] * s_sh[j];
    Ws[t] = acc;
}

__global__ __launch_bounds__(256) void final_kernel(
        const float* __restrict__ H, const float* __restrict__ Hc,
        const float* __restrict__ Ws, const float* __restrict__ bd,
        float* __restrict__ out, int n) {
    int wid = (blockIdx.x * blockDim.x + threadIdx.x) >> 6;
    if (wid >= n) return;
    int lane = threadIdx.x & 63;
    float w0 = Ws[lane], w1 = Ws[64 + lane];
    float a = H[(size_t)wid * 128 + lane] * w0 + H[(size_t)wid * 128 + 64 + lane] * w1;
    float b = Hc[(size_t)wid * 128 + lane] * w0 + Hc[(size_t)wid * 128 + 64 + lane] * w1;
    for (int off = 32; off > 0; off >>= 1) {
        a += __shfl_xor(a, off);
        b += __shfl_xor(b, off);
    }
    if (lane == 0) {
        out[wid] = a + bd[0];
        out[n + wid] = b + bd[0];
    }
}

// ---------------- launch ----------------

extern "C" void kernel_launch(void* const* d_in, const int* in_sizes, int n_in,
                              void* d_out, int out_size, void* d_ws, size_t ws_size,
                              hipStream_t stream) {
    const float* x  = (const float*)d_in[0];
    const int*   ei = (const int*)d_in[1];
    const int* perm = (const int*)d_in[2];
    const float* W1 = (const float*)d_in[3];
    const float* b1 = (const float*)d_in[4];
    const float* W2 = (const float*)d_in[5];
    const float* b2 = (const float*)d_in[6];
    const float* Wd = (const float*)d_in[7];
    const float* bd = (const float*)d_in[8];

    const int N = in_sizes[2];
    const int E = in_sizes[1] / 2;
    const int IN = in_sizes[0] / N;  // 512
    const int* src = ei;
    const int* dst = ei + E;
    float* out = (float*)d_out;

    char* p = (char*)d_ws;
    auto alloc = [&](size_t bytes) -> void* {
        void* r = (void*)p;
        p += (bytes + 511) & ~(size_t)511;
        return r;
    };
    int*   deg_i  = (int*)alloc((size_t)N * 4);
    int*   cursor = (int*)alloc((size_t)N * 4);
    int*   rp     = (int*)alloc((size_t)(N + 1) * 4);
    int*   adj    = (int*)alloc((size_t)E * 4);
    float* dinv   = (float*)alloc((size_t)N * 4);
    int*   bsum   = (int*)alloc(4096);
    int*   total  = (int*)alloc(64);
    float* colsum = (float*)alloc(512);
    float* Wsv    = (float*)alloc(512);
    ushort* W1p   = (ushort*)alloc((size_t)512 * 128 * 2);
    ushort* W2p   = (ushort*)alloc((size_t)128 * 128 * 2);
    ushort* F0 = (ushort*)alloc((size_t)N * 128 * 2);  // A, then C
    ushort* F1 = (ushort*)alloc((size_t)N * 128 * 2);  // B, then C2
    ushort* F2 = (ushort*)alloc((size_t)N * 128 * 2);  // B2
    float*  D  = (float*)alloc((size_t)N * 128 * 4);   // H
    float*  Hc = (float*)alloc((size_t)N * 128 * 4);   // Hc

    hipMemsetAsync(deg_i, 0, (size_t)N * 4, stream);
    hipMemsetAsync(cursor, 0, (size_t)N * 4, stream);
    hipMemsetAsync(colsum, 0, 512, stream);

    count_kernel<<<(E + 255) / 256, 256, 0, stream>>>(dst, deg_i, E);
    dinv_kernel<<<(N + 255) / 256, 256, 0, stream>>>(deg_i, dinv, N);

    int nb = (N + SC_C - 1) / SC_C;
    scan_part<<<nb, SC_T, 0, stream>>>(deg_i, bsum, N);
    scan_bsums<<<1, 1, 0, stream>>>(bsum, nb, total);
    scan_write<<<nb, SC_T, 0, stream>>>(deg_i, bsum, total, rp, N);
    fill_adj<<<(E + 255) / 256, 256, 0, stream>>>(src, dst, rp, cursor, adj, E);

    pack_w<<<(IN / 32) * 8, 64, 0, stream>>>(W1, W1p);
    pack_w<<<(128 / 32) * 8, 64, 0, stream>>>(W2, W2p);

    int gemm_blocks = (N + 63) / 64;
    int prop_blocks = (N + 3) / 4;

    // A = x @ W1  (bf16)
    gemm1_mfma<<<gemm_blocks, 256, 0, stream>>>(x, W1p, F0, N, IN);
    // (B, B2) = relu(prop(A)), relu(prop(A[perm]))
    prop2x<0, true, ushort><<<prop_blocks, 256, 0, stream>>>(F0, F0, rp, adj, dinv, perm, b1, F1, F2, N);
    // C = B @ W2 (into F0), C2 = B2 @ W2 (into F1 after B is dead)
    gemm2_mfma<<<gemm_blocks, 256, 0, stream>>>(F1, W2p, F0, N);
    gemm2_mfma<<<gemm_blocks, 256, 0, stream>>>(F2, W2p, F1, N);
    // (D, Hc) = prop(C), prop(C2)  (fp32 outputs)
    prop2x<1, false, float><<<prop_blocks, 256, 0, stream>>>(F0, F1, rp, adj, dinv, perm, b2, D, Hc, N);

    colsum_kernel<<<(N + 511) / 512, 128, 0, stream>>>(D, colsum, N);
    sws_kernel<<<1, 128, 0, stream>>>(colsum, Wd, Wsv, N);
    final_kernel<<<prop_blocks, 256, 0, stream>>>(D, Hc, Wsv, bd, out, N);
}

// Round 3
// 1063.077 us; speedup vs baseline: 2.1553x; 1.0002x over previous
//
#include <hip/hip_runtime.h>
#include <hip/hip_bf16.h>

typedef unsigned int uint;
typedef unsigned short ushort;
typedef __attribute__((ext_vector_type(8))) short bf16x8;
typedef __attribute__((ext_vector_type(4))) float f32x4;

static __device__ __forceinline__ ushort f2bf(float f) {
    uint u = __builtin_bit_cast(uint, f);
    return (ushort)((u + 0x7FFFu + ((u >> 16) & 1u)) >> 16);
}
static __device__ __forceinline__ uint pk2(float lo, float hi) {
    return (uint)f2bf(lo) | ((uint)f2bf(hi) << 16);
}
static __device__ __forceinline__ float bflo(uint u) { return __builtin_bit_cast(float, u << 16); }
static __device__ __forceinline__ float bfhi(uint u) { return __builtin_bit_cast(float, u & 0xFFFF0000u); }

// ---------------- CSR build ----------------

__global__ void count_kernel(const int* __restrict__ dst, int* __restrict__ deg, int E) {
    int e = blockIdx.x * blockDim.x + threadIdx.x;
    if (e < E) atomicAdd(&deg[dst[e]], 1);
}

__global__ void dinv_kernel(const int* __restrict__ deg, float* __restrict__ dinv, int n) {
    int v = blockIdx.x * blockDim.x + threadIdx.x;
    if (v < n) dinv[v] = rsqrtf((float)(deg[v] + 1));
}

#define SC_T 256
#define SC_C 1024

__global__ void scan_part(const int* __restrict__ deg, int* __restrict__ bsum, int n) {
    __shared__ int sh[SC_T];
    int t = threadIdx.x;
    int base = blockIdx.x * SC_C;
    int s = 0;
    for (int i = 0; i < 4; i++) {
        int idx = base + t * 4 + i;
        if (idx < n) s += deg[idx];
    }
    sh[t] = s;
    __syncthreads();
    for (int off = 128; off > 0; off >>= 1) {
        if (t < off) sh[t] += sh[t + off];
        __syncthreads();
    }
    if (t == 0) bsum[blockIdx.x] = sh[0];
}

__global__ void scan_bsums(int* bsum, int nb, int* total) {
    if (threadIdx.x == 0 && blockIdx.x == 0) {
        int acc = 0;
        for (int i = 0; i < nb; i++) { int v = bsum[i]; bsum[i] = acc; acc += v; }
        *total = acc;
    }
}

__global__ void scan_write(const int* __restrict__ deg, const int* __restrict__ bsum,
                           const int* __restrict__ total, int* __restrict__ rp, int n) {
    __shared__ int sh[SC_T];
    int t = threadIdx.x;
    int base = blockIdx.x * SC_C;
    int vals[4];
    int s = 0;
    for (int i = 0; i < 4; i++) {
        int idx = base + t * 4 + i;
        vals[i] = (idx < n) ? deg[idx] : 0;
        s += vals[i];
    }
    sh[t] = s;
    __syncthreads();
    for (int off = 1; off < SC_T; off <<= 1) {
        int v = (t >= off) ? sh[t - off] : 0;
        __syncthreads();
        sh[t] += v;
        __syncthreads();
    }
    int excl = sh[t] - s + bsum[blockIdx.x];
    for (int i = 0; i < 4; i++) {
        int idx = base + t * 4 + i;
        if (idx < n) { rp[idx] = excl; excl += vals[i]; }
    }
    if (blockIdx.x == 0 && t == 0) rp[n] = *total;
}

__global__ void fill_adj(const int* __restrict__ src, const int* __restrict__ dst,
                         const int* __restrict__ rp, int* __restrict__ cursor,
                         int* __restrict__ adj, int E) {
    int e = blockIdx.x * blockDim.x + threadIdx.x;
    if (e < E) {
        int d = dst[e];
        int p = atomicAdd(&cursor[d], 1);
        adj[rp[d] + p] = src[e];
    }
}

// ---------------- W pre-pack into MFMA B-fragment layout (both weights, one launch) ----------------
// Wp[((kc*8 + n)*64 + lane)*8 + j] = W[kc*32 + (lane>>4)*8 + j][n*16 + (lane&15)]

__global__ void pack_w2(const float* __restrict__ W1, ushort* __restrict__ W1p,
                        const float* __restrict__ W2, ushort* __restrict__ W2p) {
    int b = blockIdx.x;
    const float* W;
    ushort* Wp;
    if (b < 128) { W = W1; Wp = W1p; }
    else { b -= 128; W = W2; Wp = W2p; }
    int kc = b >> 3, n = b & 7;
    int l = threadIdx.x;
    ushort o[8];
#pragma unroll
    for (int j = 0; j < 8; ++j) {
        float v = W[(size_t)(kc * 32 + ((l >> 4) * 8) + j) * 128 + n * 16 + (l & 15)];
        o[j] = f2bf(v);
    }
    uint4 pk;
    pk.x = (uint)o[0] | ((uint)o[1] << 16);
    pk.y = (uint)o[2] | ((uint)o[3] << 16);
    pk.z = (uint)o[4] | ((uint)o[5] << 16);
    pk.w = (uint)o[6] | ((uint)o[7] << 16);
    *(uint4*)(Wp + ((size_t)(kc * 8 + n) * 64 + l) * 8) = pk;
}

// ---------------- GEMM1: Cb[M,128](bf16) = X[M,K](fp32) @ W1 (packed), double-buffered ----------------

__global__ __launch_bounds__(256) void gemm1_mfma(
        const float* __restrict__ X, const ushort* __restrict__ Wp,
        ushort* __restrict__ Cb, int M, int K) {
    __shared__ ushort As[2][64][40];
    int t = threadIdx.x, lane = t & 63, w = t >> 6;
    int brow = blockIdx.x * 64;
    int KC = K >> 5;
    f32x4 acc[8] = {};
    int sr = t >> 2, sk = (t & 3) * 8;
    int gr = brow + sr;
    bool xok = gr < M;
    int frow = w * 16 + (lane & 15);
    int fk = (lane >> 4) * 8;

    auto loadpk = [&](int kc) -> uint4 {
        float4 xa = make_float4(0.f, 0.f, 0.f, 0.f), xb = xa;
        if (xok) {
            const float* xp = X + (size_t)gr * K + kc * 32 + sk;
            xa = *(const float4*)xp;
            xb = *(const float4*)(xp + 4);
        }
        uint4 pk;
        pk.x = pk2(xa.x, xa.y);
        pk.y = pk2(xa.z, xa.w);
        pk.z = pk2(xb.x, xb.y);
        pk.w = pk2(xb.z, xb.w);
        return pk;
    };

    uint4 cur = loadpk(0);
    int buf = 0;
    for (int kc = 0; kc < KC; ++kc) {
        *(uint4*)&As[buf][sr][sk] = cur;
        __syncthreads();
        if (kc + 1 < KC) cur = loadpk(kc + 1);
        bf16x8 af = *(const bf16x8*)&As[buf][frow][fk];
        const ushort* wbase = Wp + ((size_t)(kc * 8) * 64 + lane) * 8;
#pragma unroll
        for (int n = 0; n < 8; ++n) {
            bf16x8 bfr = *(const bf16x8*)(wbase + (size_t)n * 64 * 8);
            acc[n] = __builtin_amdgcn_mfma_f32_16x16x32_bf16(af, bfr, acc[n], 0, 0, 0);
        }
        buf ^= 1;
    }
    int colbase = lane & 15;
    int rowbase = brow + w * 16 + ((lane >> 4) << 2);
#pragma unroll
    for (int n = 0; n < 8; ++n) {
#pragma unroll
        for (int r = 0; r < 4; ++r) {
            int grr = rowbase + r;
            if (grr < M) Cb[(size_t)grr * 128 + n * 16 + colbase] = f2bf(acc[n][r]);
        }
    }
}

// ---------------- GEMM2: Cb[M,128](bf16) = Ab[M,128](bf16) @ W (packed), K=128 ----------------

__global__ __launch_bounds__(256) void gemm2_mfma(
        const ushort* __restrict__ Ab, const ushort* __restrict__ Wp,
        ushort* __restrict__ Cb, int M) {
    int t = threadIdx.x, lane = t & 63, w = t >> 6;
    int brow = blockIdx.x * 64;
    int row16 = brow + w * 16 + (lane & 15);
    int fk = (lane >> 4) * 8;
    f32x4 acc[8] = {};
#pragma unroll
    for (int kc = 0; kc < 4; ++kc) {
        bf16x8 af = {};
        if (row16 < M) af = *(const bf16x8*)(Ab + (size_t)row16 * 128 + kc * 32 + fk);
        const ushort* wbase = Wp + ((size_t)(kc * 8) * 64 + lane) * 8;
#pragma unroll
        for (int n = 0; n < 8; ++n) {
            bf16x8 bfr = *(const bf16x8*)(wbase + (size_t)n * 64 * 8);
            acc[n] = __builtin_amdgcn_mfma_f32_16x16x32_bf16(af, bfr, acc[n], 0, 0, 0);
        }
    }
    int colbase = lane & 15;
    int rowbase = brow + w * 16 + ((lane >> 4) << 2);
#pragma unroll
    for (int n = 0; n < 8; ++n) {
#pragma unroll
        for (int r = 0; r < 4; ++r) {
            int grr = rowbase + r;
            if (grr < M) Cb[(size_t)grr * 128 + n * 16 + colbase] = f2bf(acc[n][r]);
        }
    }
}

// ---------------- fused dual propagation: 4 nodes/wave, 16B gathers ----------------
// MODE 0: P1 indexed through perm (layer 1, P0==P1==A). MODE 1: two matrices, same index.

#define ACC8(acc, g, w)                                   \
    acc[0] += bflo(g.x) * w; acc[1] += bfhi(g.x) * w;     \
    acc[2] += bflo(g.y) * w; acc[3] += bfhi(g.y) * w;     \
    acc[4] += bflo(g.z) * w; acc[5] += bfhi(g.z) * w;     \
    acc[6] += bflo(g.w) * w; acc[7] += bfhi(g.w) * w;

template <int MODE, bool RELU, typename OT>
__global__ __launch_bounds__(256) void prop4(
        const ushort* __restrict__ P0, const ushort* __restrict__ P1,
        const int* __restrict__ rp, const int* __restrict__ adj,
        const float* __restrict__ dinv, const int* __restrict__ perm,
        const float* __restrict__ bias,
        OT* __restrict__ O0, OT* __restrict__ O1, int n) {
    int wave = (blockIdx.x * blockDim.x + threadIdx.x) >> 6;
    int lane = threadIdx.x & 63;
    int q = lane >> 4, l = lane & 15;
    int v = wave * 4 + q;
    bool vok = v < n;
    int vc = vok ? v : (n - 1);
    float dv = dinv[vc];
    int s1 = (MODE == 0) ? perm[vc] : vc;

    uint4 r0 = *(const uint4*)(P0 + (size_t)vc * 128 + 8 * l);
    uint4 r1 = *(const uint4*)(P1 + (size_t)s1 * 128 + 8 * l);
    float a0[8], a1[8];
    ACC8_INIT:;
    a0[0] = bflo(r0.x) * dv; a0[1] = bfhi(r0.x) * dv;
    a0[2] = bflo(r0.y) * dv; a0[3] = bfhi(r0.y) * dv;
    a0[4] = bflo(r0.z) * dv; a0[5] = bfhi(r0.z) * dv;
    a0[6] = bflo(r0.w) * dv; a0[7] = bfhi(r0.w) * dv;
    a1[0] = bflo(r1.x) * dv; a1[1] = bfhi(r1.x) * dv;
    a1[2] = bflo(r1.y) * dv; a1[3] = bfhi(r1.y) * dv;
    a1[4] = bflo(r1.z) * dv; a1[5] = bfhi(r1.z) * dv;
    a1[6] = bflo(r1.w) * dv; a1[7] = bfhi(r1.w) * dv;

    int i = rp[vc], end = rp[vc + 1];
    int un[4];
#pragma unroll
    for (int k = 0; k < 4; ++k) un[k] = (i + k < end) ? adj[i + k] : vc;

    while (__ballot(i < end)) {
        int uc[4];
#pragma unroll
        for (int k = 0; k < 4; ++k) uc[k] = un[k];
        // issue feature gathers for P0 immediately
        uint4 g0[4];
#pragma unroll
        for (int k = 0; k < 4; ++k) g0[k] = *(const uint4*)(P0 + (size_t)uc[k] * 128 + 8 * l);
        int uu[4];
#pragma unroll
        for (int k = 0; k < 4; ++k) uu[k] = (MODE == 0) ? perm[uc[k]] : uc[k];
        uint4 g1[4];
#pragma unroll
        for (int k = 0; k < 4; ++k) g1[k] = *(const uint4*)(P1 + (size_t)uu[k] * 128 + 8 * l);
        float du[4];
#pragma unroll
        for (int k = 0; k < 4; ++k) du[k] = (i + k < end) ? dinv[uc[k]] : 0.f;
        i += 4;
        // prefetch next batch's adjacency off the critical path
#pragma unroll
        for (int k = 0; k < 4; ++k) un[k] = (i + k < end) ? adj[i + k] : vc;
#pragma unroll
        for (int k = 0; k < 4; ++k) {
            float w = du[k];
            ACC8(a0, g0[k], w)
            ACC8(a1, g1[k], w)
        }
    }
    if (!vok) return;
    float4 bA = *(const float4*)(bias + 8 * l);
    float4 bB = *(const float4*)(bias + 8 * l + 4);
    float bb[8] = {bA.x, bA.y, bA.z, bA.w, bB.x, bB.y, bB.z, bB.w};
#pragma unroll
    for (int j = 0; j < 8; ++j) {
        a0[j] = a0[j] * dv + bb[j];
        a1[j] = a1[j] * dv + bb[j];
        if (RELU) { a0[j] = fmaxf(a0[j], 0.f); a1[j] = fmaxf(a1[j], 0.f); }
    }
    if constexpr (sizeof(OT) == 2) {
        uint4 o;
        o.x = pk2(a0[0], a0[1]); o.y = pk2(a0[2], a0[3]);
        o.z = pk2(a0[4], a0[5]); o.w = pk2(a0[6], a0[7]);
        *(uint4*)((ushort*)O0 + (size_t)v * 128 + 8 * l) = o;
        o.x = pk2(a1[0], a1[1]); o.y = pk2(a1[2], a1[3]);
        o.z = pk2(a1[4], a1[5]); o.w = pk2(a1[6], a1[7]);
        *(uint4*)((ushort*)O1 + (size_t)v * 128 + 8 * l) = o;
    } else {
        float* p0 = (float*)O0 + (size_t)v * 128 + 8 * l;
        float* p1 = (float*)O1 + (size_t)v * 128 + 8 * l;
        *(float4*)p0 = make_float4(a0[0], a0[1], a0[2], a0[3]);
        *(float4*)(p0 + 4) = make_float4(a0[4], a0[5], a0[6], a0[7]);
        *(float4*)p1 = make_float4(a1[0], a1[1], a1[2], a1[3]);
        *(float4*)(p1 + 4) = make_float4(a1[4], a1[5], a1[6], a1[7]);
    }
}

// ---------------- readout ----------------

__global__ void colsum_kernel(const float* __restrict__ H, float* __restrict__ colsum, int n) {
    int t = threadIdx.x;  // 128
    int r0 = blockIdx.x * 512;
    int r1 = min(r0 + 512, n);
    float acc = 0.f;
    for (int r = r0; r < r1; ++r) acc += H[(size_t)r * 128 + t];
    atomicAdd(&colsum[t], acc);
}

__global__ void sws_kernel(const float* __restrict__ colsum, const float* __restrict__ Wd,
                           float* __restrict__ Ws, int n) {
    __shared__ float s_sh[128];
    int t = threadIdx.x;  // 128
    float m = colsum[t] / (float)n;
    s_sh[t] = 1.f / (1.f + expf(-m));
    __syncthreads();
    float acc = 0.f;
    for (int j = 0; j < 128; ++j) acc += Wd[t * 128 + j] * s_sh[j];
    Ws[t] = acc;
}

__global__ __launch_bounds__(256) void final_kernel(
        const float* __restrict__ H, const float* __restrict__ Hc,
        const float* __restrict__ Ws, const float* __restrict__ bd,
        float* __restrict__ out, int n) {
    int wid = (blockIdx.x * blockDim.x + threadIdx.x) >> 6;
    if (wid >= n) return;
    int lane = threadIdx.x & 63;
    float w0 = Ws[lane], w1 = Ws[64 + lane];
    float a = H[(size_t)wid * 128 + lane] * w0 + H[(size_t)wid * 128 + 64 + lane] * w1;
    float b = Hc[(size_t)wid * 128 + lane] * w0 + Hc[(size_t)wid * 128 + 64 + lane] * w1;
    for (int off = 32; off > 0; off >>= 1) {
        a += __shfl_xor(a, off);
        b += __shfl_xor(b, off);
    }
    if (lane == 0) {
        out[wid] = a + bd[0];
        out[n + wid] = b + bd[0];
    }
}

// ---------------- launch ----------------

extern "C" void kernel_launch(void* const* d_in, const int* in_sizes, int n_in,
                              void* d_out, int out_size, void* d_ws, size_t ws_size,
                              hipStream_t stream) {
    const float* x  = (const float*)d_in[0];
    const int*   ei = (const int*)d_in[1];
    const int* perm = (const int*)d_in[2];
    const float* W1 = (const float*)d_in[3];
    const float* b1 = (const float*)d_in[4];
    const float* W2 = (const float*)d_in[5];
    const float* b2 = (const float*)d_in[6];
    const float* Wd = (const float*)d_in[7];
    const float* bd = (const float*)d_in[8];

    const int N = in_sizes[2];
    const int E = in_sizes[1] / 2;
    const int IN = in_sizes[0] / N;  // 512
    const int* src = ei;
    const int* dst = ei + E;
    float* out = (float*)d_out;

    char* p = (char*)d_ws;
    auto alloc = [&](size_t bytes) -> void* {
        void* r = (void*)p;
        p += (bytes + 511) & ~(size_t)511;
        return r;
    };
    int*   deg_i  = (int*)alloc((size_t)N * 4);
    int*   cursor = (int*)alloc((size_t)N * 4);
    int*   rp     = (int*)alloc((size_t)(N + 1) * 4);
    int*   adj    = (int*)alloc((size_t)E * 4);
    float* dinv   = (float*)alloc((size_t)N * 4);
    int*   bsum   = (int*)alloc(4096);
    int*   total  = (int*)alloc(64);
    float* colsum = (float*)alloc(512);
    float* Wsv    = (float*)alloc(512);
    ushort* W1p   = (ushort*)alloc((size_t)512 * 128 * 2);
    ushort* W2p   = (ushort*)alloc((size_t)128 * 128 * 2);
    ushort* F0 = (ushort*)alloc((size_t)N * 128 * 2);  // A, then C
    ushort* F1 = (ushort*)alloc((size_t)N * 128 * 2);  // B, then C2
    ushort* F2 = (ushort*)alloc((size_t)N * 128 * 2);  // B2
    float*  D  = (float*)alloc((size_t)N * 128 * 4);   // H
    float*  Hc = (float*)alloc((size_t)N * 128 * 4);   // Hc

    hipMemsetAsync(deg_i, 0, (size_t)N * 4, stream);
    hipMemsetAsync(cursor, 0, (size_t)N * 4, stream);
    hipMemsetAsync(colsum, 0, 512, stream);

    count_kernel<<<(E + 255) / 256, 256, 0, stream>>>(dst, deg_i, E);
    dinv_kernel<<<(N + 255) / 256, 256, 0, stream>>>(deg_i, dinv, N);

    int nb = (N + SC_C - 1) / SC_C;
    scan_part<<<nb, SC_T, 0, stream>>>(deg_i, bsum, N);
    scan_bsums<<<1, 1, 0, stream>>>(bsum, nb, total);
    scan_write<<<nb, SC_T, 0, stream>>>(deg_i, bsum, total, rp, N);
    fill_adj<<<(E + 255) / 256, 256, 0, stream>>>(src, dst, rp, cursor, adj, E);

    pack_w2<<<(IN / 32) * 8 + 32, 64, 0, stream>>>(W1, W1p, W2, W2p);

    int gemm_blocks = (N + 63) / 64;
    int fin_blocks = (N + 3) / 4;
    int waves4 = (N + 3) / 4;
    int p4_blocks = (waves4 + 3) / 4;

    // A = x @ W1  (bf16)
    gemm1_mfma<<<gemm_blocks, 256, 0, stream>>>(x, W1p, F0, N, IN);
    // (B, B2) = relu(prop(A)), relu(prop(A[perm]))
    prop4<0, true, ushort><<<p4_blocks, 256, 0, stream>>>(F0, F0, rp, adj, dinv, perm, b1, F1, F2, N);
    // C = B @ W2 (into F0), C2 = B2 @ W2 (into F1 after B is dead)
    gemm2_mfma<<<gemm_blocks, 256, 0, stream>>>(F1, W2p, F0, N);
    gemm2_mfma<<<gemm_blocks, 256, 0, stream>>>(F2, W2p, F1, N);
    // (D, Hc) = prop(C), prop(C2)  (fp32 outputs)
    prop4<1, false, float><<<p4_blocks, 256, 0, stream>>>(F0, F1, rp, adj, dinv, perm, b2, D, Hc, N);

    colsum_kernel<<<(N + 511) / 512, 128, 0, stream>>>(D, colsum, N);
    sws_kernel<<<1, 128, 0, stream>>>(colsum, Wd, Wsv, N);
    final_kernel<<<fin_blocks, 256, 0, stream>>>(D, Hc, Wsv, bd, out, N);
}

// Round 4
// 853.386 us; speedup vs baseline: 2.6849x; 1.2457x over previous
//
#include <hip/hip_runtime.h>
#include <hip/hip_bf16.h>

typedef unsigned int uint;
typedef unsigned short ushort;
typedef __attribute__((ext_vector_type(8))) short bf16x8;
typedef __attribute__((ext_vector_type(4))) float f32x4;

static __device__ __forceinline__ ushort f2bf(float f) {
    uint u = __builtin_bit_cast(uint, f);
    return (ushort)((u + 0x7FFFu + ((u >> 16) & 1u)) >> 16);
}
static __device__ __forceinline__ uint pk2(float lo, float hi) {
    return (uint)f2bf(lo) | ((uint)f2bf(hi) << 16);
}
static __device__ __forceinline__ float bflo(uint u) { return __builtin_bit_cast(float, u << 16); }
static __device__ __forceinline__ float bfhi(uint u) { return __builtin_bit_cast(float, u & 0xFFFF0000u); }

// ---------------- CSR build ----------------

__global__ void count_kernel(const int* __restrict__ dst, int* __restrict__ deg, int E) {
    int i = blockIdx.x * blockDim.x + threadIdx.x;
    int e = i * 4;
    if (e + 4 <= E) {
        int4 d = *(const int4*)(dst + e);
        atomicAdd(&deg[d.x], 1);
        atomicAdd(&deg[d.y], 1);
        atomicAdd(&deg[d.z], 1);
        atomicAdd(&deg[d.w], 1);
    } else {
        for (; e < E; ++e) atomicAdd(&deg[dst[e]], 1);
    }
}

__global__ void dinv_kernel(const int* __restrict__ deg, float* __restrict__ dinv, int n) {
    int v = blockIdx.x * blockDim.x + threadIdx.x;
    if (v < n) dinv[v] = rsqrtf((float)(deg[v] + 1));
}

#define SC_T 256
#define SC_C 1024

__global__ void scan_part(const int* __restrict__ deg, int* __restrict__ bsum, int n) {
    __shared__ int sh[SC_T];
    int t = threadIdx.x;
    int base = blockIdx.x * SC_C;
    int s = 0;
    for (int i = 0; i < 4; i++) {
        int idx = base + t * 4 + i;
        if (idx < n) s += deg[idx];
    }
    sh[t] = s;
    __syncthreads();
    for (int off = 128; off > 0; off >>= 1) {
        if (t < off) sh[t] += sh[t + off];
        __syncthreads();
    }
    if (t == 0) bsum[blockIdx.x] = sh[0];
}

__global__ void scan_bsums(int* bsum, int nb, int* total) {
    if (threadIdx.x == 0 && blockIdx.x == 0) {
        int acc = 0;
        for (int i = 0; i < nb; i++) { int v = bsum[i]; bsum[i] = acc; acc += v; }
        *total = acc;
    }
}

__global__ void scan_write(const int* __restrict__ deg, const int* __restrict__ bsum,
                           const int* __restrict__ total, int* __restrict__ rp, int n) {
    __shared__ int sh[SC_T];
    int t = threadIdx.x;
    int base = blockIdx.x * SC_C;
    int vals[4];
    int s = 0;
    for (int i = 0; i < 4; i++) {
        int idx = base + t * 4 + i;
        vals[i] = (idx < n) ? deg[idx] : 0;
        s += vals[i];
    }
    sh[t] = s;
    __syncthreads();
    for (int off = 1; off < SC_T; off <<= 1) {
        int v = (t >= off) ? sh[t - off] : 0;
        __syncthreads();
        sh[t] += v;
        __syncthreads();
    }
    int excl = sh[t] - s + bsum[blockIdx.x];
    for (int i = 0; i < 4; i++) {
        int idx = base + t * 4 + i;
        if (idx < n) { rp[idx] = excl; excl += vals[i]; }
    }
    if (blockIdx.x == 0 && t == 0) rp[n] = *total;
}

// fill adjacency + accumulate t-weights: tw[src] += dinv[dst]
__global__ void fill_tw(const int* __restrict__ src, const int* __restrict__ dst,
                        const int* __restrict__ rp, int* __restrict__ cursor,
                        const float* __restrict__ dinv,
                        int* __restrict__ adj, float* __restrict__ tw, int E) {
    int e = blockIdx.x * blockDim.x + threadIdx.x;
    if (e < E) {
        int d = dst[e];
        int s = src[e];
        int p = atomicAdd(&cursor[d], 1);
        adj[rp[d] + p] = s;
        atomicAdd(&tw[s], dinv[d]);
    }
}

// ---------------- W1 pre-pack into MFMA B-fragment layout ----------------
// Wp[((kc*8 + n)*64 + lane)*8 + j] = W[kc*32 + (lane>>4)*8 + j][n*16 + (lane&15)]

__global__ void pack_w(const float* __restrict__ W, ushort* __restrict__ Wp) {
    int kc = blockIdx.x >> 3, n = blockIdx.x & 7;
    int l = threadIdx.x;
    ushort o[8];
#pragma unroll
    for (int j = 0; j < 8; ++j) {
        float v = W[(size_t)(kc * 32 + ((l >> 4) * 8) + j) * 128 + n * 16 + (l & 15)];
        o[j] = f2bf(v);
    }
    uint4 pk;
    pk.x = (uint)o[0] | ((uint)o[1] << 16);
    pk.y = (uint)o[2] | ((uint)o[3] << 16);
    pk.z = (uint)o[4] | ((uint)o[5] << 16);
    pk.w = (uint)o[6] | ((uint)o[7] << 16);
    *(uint4*)(Wp + ((size_t)(kc * 8 + n) * 64 + l) * 8) = pk;
}

// ---------------- GEMM1: Cb[M,128](bf16) = X[M,K](fp32) @ W1 (packed), double-buffered ----------------

__global__ __launch_bounds__(256) void gemm1_mfma(
        const float* __restrict__ X, const ushort* __restrict__ Wp,
        ushort* __restrict__ Cb, int M, int K) {
    __shared__ ushort As[2][64][40];
    int t = threadIdx.x, lane = t & 63, w = t >> 6;
    int brow = blockIdx.x * 64;
    int KC = K >> 5;
    f32x4 acc[8] = {};
    int sr = t >> 2, sk = (t & 3) * 8;
    int gr = brow + sr;
    bool xok = gr < M;
    int frow = w * 16 + (lane & 15);
    int fk = (lane >> 4) * 8;

    auto loadpk = [&](int kc) -> uint4 {
        float4 xa = make_float4(0.f, 0.f, 0.f, 0.f), xb = xa;
        if (xok) {
            const float* xp = X + (size_t)gr * K + kc * 32 + sk;
            xa = *(const float4*)xp;
            xb = *(const float4*)(xp + 4);
        }
        uint4 pk;
        pk.x = pk2(xa.x, xa.y);
        pk.y = pk2(xa.z, xa.w);
        pk.z = pk2(xb.x, xb.y);
        pk.w = pk2(xb.z, xb.w);
        return pk;
    };

    uint4 cur = loadpk(0);
    int buf = 0;
    for (int kc = 0; kc < KC; ++kc) {
        *(uint4*)&As[buf][sr][sk] = cur;
        __syncthreads();
        if (kc + 1 < KC) cur = loadpk(kc + 1);
        bf16x8 af = *(const bf16x8*)&As[buf][frow][fk];
        const ushort* wbase = Wp + ((size_t)(kc * 8) * 64 + lane) * 8;
#pragma unroll
        for (int n = 0; n < 8; ++n) {
            bf16x8 bfr = *(const bf16x8*)(wbase + (size_t)n * 64 * 8);
            acc[n] = __builtin_amdgcn_mfma_f32_16x16x32_bf16(af, bfr, acc[n], 0, 0, 0);
        }
        buf ^= 1;
    }
    int colbase = lane & 15;
    int rowbase = brow + w * 16 + ((lane >> 4) << 2);
#pragma unroll
    for (int n = 0; n < 8; ++n) {
#pragma unroll
        for (int r = 0; r < 4; ++r) {
            int grr = rowbase + r;
            if (grr < M) Cb[(size_t)grr * 128 + n * 16 + colbase] = f2bf(acc[n][r]);
        }
    }
}

// ---------------- layer-1 dual propagation: 4 nodes/wave, 16B gathers ----------------
// (B,B2) = relu(prop(A) + b1), relu(prop_perm(A) + b1)

#define ACC8(acc, g, w)                                   \
    acc[0] += bflo(g.x) * w; acc[1] += bfhi(g.x) * w;     \
    acc[2] += bflo(g.y) * w; acc[3] += bfhi(g.y) * w;     \
    acc[4] += bflo(g.z) * w; acc[5] += bfhi(g.z) * w;     \
    acc[6] += bflo(g.w) * w; acc[7] += bfhi(g.w) * w;

__global__ __launch_bounds__(256) void prop4_l1(
        const ushort* __restrict__ P0,
        const int* __restrict__ rp, const int* __restrict__ adj,
        const float* __restrict__ dinv, const int* __restrict__ perm,
        const float* __restrict__ bias,
        ushort* __restrict__ O0, ushort* __restrict__ O1, int n) {
    int wave = (blockIdx.x * blockDim.x + threadIdx.x) >> 6;
    int lane = threadIdx.x & 63;
    int q = lane >> 4, l = lane & 15;
    int v = wave * 4 + q;
    bool vok = v < n;
    int vc = vok ? v : (n - 1);
    float dv = dinv[vc];
    int s1 = perm[vc];

    uint4 r0 = *(const uint4*)(P0 + (size_t)vc * 128 + 8 * l);
    uint4 r1 = *(const uint4*)(P0 + (size_t)s1 * 128 + 8 * l);
    float a0[8], a1[8];
    a0[0] = bflo(r0.x) * dv; a0[1] = bfhi(r0.x) * dv;
    a0[2] = bflo(r0.y) * dv; a0[3] = bfhi(r0.y) * dv;
    a0[4] = bflo(r0.z) * dv; a0[5] = bfhi(r0.z) * dv;
    a0[6] = bflo(r0.w) * dv; a0[7] = bfhi(r0.w) * dv;
    a1[0] = bflo(r1.x) * dv; a1[1] = bfhi(r1.x) * dv;
    a1[2] = bflo(r1.y) * dv; a1[3] = bfhi(r1.y) * dv;
    a1[4] = bflo(r1.z) * dv; a1[5] = bfhi(r1.z) * dv;
    a1[6] = bflo(r1.w) * dv; a1[7] = bfhi(r1.w) * dv;

    int i = rp[vc], end = rp[vc + 1];
    int un[4];
#pragma unroll
    for (int k = 0; k < 4; ++k) un[k] = (i + k < end) ? adj[i + k] : vc;

    while (__ballot(i < end)) {
        int uc[4];
#pragma unroll
        for (int k = 0; k < 4; ++k) uc[k] = un[k];
        uint4 g0[4];
#pragma unroll
        for (int k = 0; k < 4; ++k) g0[k] = *(const uint4*)(P0 + (size_t)uc[k] * 128 + 8 * l);
        int uu[4];
#pragma unroll
        for (int k = 0; k < 4; ++k) uu[k] = perm[uc[k]];
        uint4 g1[4];
#pragma unroll
        for (int k = 0; k < 4; ++k) g1[k] = *(const uint4*)(P0 + (size_t)uu[k] * 128 + 8 * l);
        float du[4];
#pragma unroll
        for (int k = 0; k < 4; ++k) du[k] = (i + k < end) ? dinv[uc[k]] : 0.f;
        i += 4;
#pragma unroll
        for (int k = 0; k < 4; ++k) un[k] = (i + k < end) ? adj[i + k] : vc;
#pragma unroll
        for (int k = 0; k < 4; ++k) {
            float w = du[k];
            ACC8(a0, g0[k], w)
            ACC8(a1, g1[k], w)
        }
    }
    if (!vok) return;
    float4 bA = *(const float4*)(bias + 8 * l);
    float4 bB = *(const float4*)(bias + 8 * l + 4);
    float bb[8] = {bA.x, bA.y, bA.z, bA.w, bB.x, bB.y, bB.z, bB.w};
#pragma unroll
    for (int j = 0; j < 8; ++j) {
        a0[j] = fmaxf(a0[j] * dv + bb[j], 0.f);
        a1[j] = fmaxf(a1[j] * dv + bb[j], 0.f);
    }
    uint4 o;
    o.x = pk2(a0[0], a0[1]); o.y = pk2(a0[2], a0[3]);
    o.z = pk2(a0[4], a0[5]); o.w = pk2(a0[6], a0[7]);
    *(uint4*)(O0 + (size_t)v * 128 + 8 * l) = o;
    o.x = pk2(a1[0], a1[1]); o.y = pk2(a1[2], a1[3]);
    o.z = pk2(a1[4], a1[5]); o.w = pk2(a1[6], a1[7]);
    *(uint4*)(O1 + (size_t)v * 128 + 8 * l) = o;
}

// ---------------- weighted colsum: mBvec[j] = sum_u t_u * B[u][j], t_u = dinv[u]*(tw[u]+dinv[u]) ----------------

__global__ __launch_bounds__(256) void wcolsum(
        const ushort* __restrict__ B, const float* __restrict__ tw,
        const float* __restrict__ dinv, float* __restrict__ mBvec, int n) {
    __shared__ float sh[4][128];
    int t = threadIdx.x;
    int cp = t & 63;           // column pair
    int rg = t >> 6;           // row group 0..3
    int r0 = blockIdx.x * 512;
    int r1 = min(r0 + 512, n);
    float acc0 = 0.f, acc1 = 0.f;
    for (int r = r0 + rg; r < r1; r += 4) {
        float tv = dinv[r] * (tw[r] + dinv[r]);
        uint b = *(const uint*)(B + (size_t)r * 128 + 2 * cp);
        acc0 += bflo(b) * tv;
        acc1 += bfhi(b) * tv;
    }
    sh[rg][2 * cp] = acc0;
    sh[rg][2 * cp + 1] = acc1;
    __syncthreads();
    if (t < 128) {
        float s = sh[0][t] + sh[1][t] + sh[2][t] + sh[3][t];
        atomicAdd(&mBvec[t], s);
    }
}

// ---------------- tiny: m -> s -> Ws -> w2s, k0 (one block, 128 threads) ----------------

__global__ void tiny_chain(const float* __restrict__ mBvec, const float* __restrict__ W2,
                           const float* __restrict__ b2, const float* __restrict__ Wd,
                           const float* __restrict__ bd,
                           float* __restrict__ w2s, float* __restrict__ k0, int n) {
    __shared__ float s_sh[128];
    __shared__ float ws_sh[128];
    __shared__ float red[128];
    int t = threadIdx.x;
    // m_j = mBvec @ W2 / N + b2
    float acc = 0.f;
    for (int k = 0; k < 128; ++k) acc += mBvec[k] * W2[k * 128 + t];
    float m = acc / (float)n + b2[t];
    s_sh[t] = 1.f / (1.f + expf(-m));
    __syncthreads();
    // Ws_i = Wd[i] . s
    acc = 0.f;
    for (int j = 0; j < 128; ++j) acc += Wd[t * 128 + j] * s_sh[j];
    ws_sh[t] = acc;
    __syncthreads();
    // w2s_k = W2[k] . Ws
    acc = 0.f;
    for (int j = 0; j < 128; ++j) acc += W2[t * 128 + j] * ws_sh[j];
    w2s[t] = acc;
    // k0 = b2 . Ws + bd
    red[t] = b2[t] * ws_sh[t];
    __syncthreads();
    for (int off = 64; off > 0; off >>= 1) {
        if (t < off) red[t] += red[t + off];
        __syncthreads();
    }
    if (t == 0) *k0 = red[0] + bd[0];
}

// ---------------- cdot: c0p[u] = dinv[u]*(B[u].w2s), c1p[u] = dinv[u]*(B2[u].w2s) ----------------

__global__ __launch_bounds__(256) void cdot(
        const ushort* __restrict__ B, const ushort* __restrict__ B2,
        const float* __restrict__ w2s, const float* __restrict__ dinv,
        float* __restrict__ c0p, float* __restrict__ c1p, int n) {
    int wave = (blockIdx.x * blockDim.x + threadIdx.x) >> 6;
    int lane = threadIdx.x & 63;
    if (wave >= n) return;
    float w0 = w2s[2 * lane], w1 = w2s[2 * lane + 1];
    uint b = *(const uint*)(B + (size_t)wave * 128 + 2 * lane);
    uint c = *(const uint*)(B2 + (size_t)wave * 128 + 2 * lane);
    float a = bflo(b) * w0 + bfhi(b) * w1;
    float d = bflo(c) * w0 + bfhi(c) * w1;
#pragma unroll
    for (int off = 32; off > 0; off >>= 1) {
        a += __shfl_xor(a, off);
        d += __shfl_xor(d, off);
    }
    if (lane == 0) {
        float dv = dinv[wave];
        c0p[wave] = dv * a;
        c1p[wave] = dv * d;
    }
}

// ---------------- scalar propagation: out = dv*(c'[v] + sum_u c'[u]) + k0 ----------------

__global__ __launch_bounds__(256) void sprop(
        const float* __restrict__ c0p, const float* __restrict__ c1p,
        const int* __restrict__ rp, const int* __restrict__ adj,
        const float* __restrict__ dinv, const float* __restrict__ k0,
        float* __restrict__ out, int n) {
    int wave = (blockIdx.x * blockDim.x + threadIdx.x) >> 6;
    int lane = threadIdx.x & 63;
    int q = lane >> 4, l = lane & 15;
    int v = wave * 4 + q;
    if (v >= n) return;
    float a0 = 0.f, a1 = 0.f;
    int beg = rp[v], end = rp[v + 1];
    for (int i = beg + l; i < end; i += 16) {
        int u = adj[i];
        a0 += c0p[u];
        a1 += c1p[u];
    }
#pragma unroll
    for (int off = 1; off < 16; off <<= 1) {
        a0 += __shfl_xor(a0, off);
        a1 += __shfl_xor(a1, off);
    }
    if (l == 0) {
        float dv = dinv[v];
        float kk = *k0;
        out[v] = dv * (a0 + c0p[v]) + kk;
        out[n + v] = dv * (a1 + c1p[v]) + kk;
    }
}

// ---------------- launch ----------------

extern "C" void kernel_launch(void* const* d_in, const int* in_sizes, int n_in,
                              void* d_out, int out_size, void* d_ws, size_t ws_size,
                              hipStream_t stream) {
    const float* x  = (const float*)d_in[0];
    const int*   ei = (const int*)d_in[1];
    const int* perm = (const int*)d_in[2];
    const float* W1 = (const float*)d_in[3];
    const float* b1 = (const float*)d_in[4];
    const float* W2 = (const float*)d_in[5];
    const float* b2 = (const float*)d_in[6];
    const float* Wd = (const float*)d_in[7];
    const float* bd = (const float*)d_in[8];

    const int N = in_sizes[2];
    const int E = in_sizes[1] / 2;
    const int IN = in_sizes[0] / N;  // 512
    const int* src = ei;
    const int* dst = ei + E;
    float* out = (float*)d_out;

    char* p = (char*)d_ws;
    auto alloc = [&](size_t bytes) -> void* {
        void* r = (void*)p;
        p += (bytes + 511) & ~(size_t)511;
        return r;
    };
    // zero-init group (contiguous, single memset)
    int*   deg_i  = (int*)alloc((size_t)N * 4);
    int*   cursor = (int*)alloc((size_t)N * 4);
    float* tw     = (float*)alloc((size_t)N * 4);
    float* mBvec  = (float*)alloc(512);
    size_t zspan = (size_t)((char*)p - (char*)deg_i);
    // rest
    int*   rp     = (int*)alloc((size_t)(N + 1) * 4);
    int*   adj    = (int*)alloc((size_t)E * 4);
    float* dinv   = (float*)alloc((size_t)N * 4);
    int*   bsum   = (int*)alloc(4096);
    int*   total  = (int*)alloc(64);
    float* w2sv   = (float*)alloc(512);
    float* k0v    = (float*)alloc(64);
    float* c0p    = (float*)alloc((size_t)N * 4);
    float* c1p    = (float*)alloc((size_t)N * 4);
    ushort* W1p   = (ushort*)alloc((size_t)512 * 128 * 2);
    ushort* A  = (ushort*)alloc((size_t)N * 128 * 2);
    ushort* B  = (ushort*)alloc((size_t)N * 128 * 2);
    ushort* B2 = (ushort*)alloc((size_t)N * 128 * 2);

    hipMemsetAsync(deg_i, 0, zspan, stream);

    count_kernel<<<(E / 4 + 255) / 256, 256, 0, stream>>>(dst, deg_i, E);
    dinv_kernel<<<(N + 255) / 256, 256, 0, stream>>>(deg_i, dinv, N);

    int nb = (N + SC_C - 1) / SC_C;
    scan_part<<<nb, SC_T, 0, stream>>>(deg_i, bsum, N);
    scan_bsums<<<1, 1, 0, stream>>>(bsum, nb, total);
    scan_write<<<nb, SC_T, 0, stream>>>(deg_i, bsum, total, rp, N);
    fill_tw<<<(E + 255) / 256, 256, 0, stream>>>(src, dst, rp, cursor, dinv, adj, tw, E);

    pack_w<<<(IN / 32) * 8, 64, 0, stream>>>(W1, W1p);

    int gemm_blocks = (N + 63) / 64;
    int p4_blocks = ((N + 3) / 4 + 3) / 4;   // 4 nodes/wave, 4 waves/block

    // A = bf16(x @ W1)
    gemm1_mfma<<<gemm_blocks, 256, 0, stream>>>(x, W1p, A, N, IN);
    // (B, B2) = relu(prop(A)+b1), relu(prop(A[perm])+b1)
    prop4_l1<<<p4_blocks, 256, 0, stream>>>(A, rp, adj, dinv, perm, b1, B, B2, N);
    // mBvec = sum_u t_u B[u]
    wcolsum<<<(N + 511) / 512, 256, 0, stream>>>(B, tw, dinv, mBvec, N);
    // s, Ws, w2s, k0
    tiny_chain<<<1, 128, 0, stream>>>(mBvec, W2, b2, Wd, bd, w2sv, k0v, N);
    // per-node scalars
    cdot<<<(N + 3) / 4, 256, 0, stream>>>(B, B2, w2sv, dinv, c0p, c1p, N);
    // pos/neg via scalar propagation
    sprop<<<p4_blocks, 256, 0, stream>>>(c0p, c1p, rp, adj, dinv, k0v, out, N);
}

// Round 5
// 704.628 us; speedup vs baseline: 3.2517x; 1.2111x over previous
//
#include <hip/hip_runtime.h>
#include <hip/hip_bf16.h>

typedef unsigned int uint;
typedef unsigned short ushort;
typedef __attribute__((ext_vector_type(8))) short bf16x8;
typedef __attribute__((ext_vector_type(4))) float f32x4;

static __device__ __forceinline__ ushort f2bf(float f) {
    uint u = __builtin_bit_cast(uint, f);
    return (ushort)((u + 0x7FFFu + ((u >> 16) & 1u)) >> 16);
}
static __device__ __forceinline__ uint pk2(float lo, float hi) {
    return (uint)f2bf(lo) | ((uint)f2bf(hi) << 16);
}
static __device__ __forceinline__ float bflo(uint u) { return __builtin_bit_cast(float, u << 16); }
static __device__ __forceinline__ float bfhi(uint u) { return __builtin_bit_cast(float, u & 0xFFFF0000u); }

// ================= CSR build via two-level counting sort =================
// bucket = dst >> 8 (256 nodes per bucket). NB <= 512 (N <= 131072).

#define CS_G 512   // partition grid

__global__ __launch_bounds__(256) void part_hist(
        const int* __restrict__ dst, uint* __restrict__ counts,
        int E, int NB, int chunk) {
    __shared__ uint h[512];
    int t = threadIdx.x;
    for (int b = t; b < NB; b += 256) h[b] = 0;
    __syncthreads();
    int s0 = blockIdx.x * chunk;
    int s1 = min(s0 + chunk, E);
    for (int i = s0 + t; i < s1; i += 256) {
        atomicAdd(&h[dst[i] >> 8], 1u);
    }
    __syncthreads();
    for (int b = t; b < NB; b += 256)
        counts[(size_t)b * CS_G + blockIdx.x] = h[b];
}

__global__ __launch_bounds__(256) void part_scatter(
        const int* __restrict__ src, const int* __restrict__ dst,
        const uint* __restrict__ scn, uint* __restrict__ rec,
        int E, int NB, int chunk) {
    __shared__ uint cur[512];
    int t = threadIdx.x;
    for (int b = t; b < NB; b += 256) cur[b] = scn[(size_t)b * CS_G + blockIdx.x];
    __syncthreads();
    int s0 = blockIdx.x * chunk;
    int s1 = min(s0 + chunk, E);
    for (int i = s0 + t; i < s1; i += 256) {
        int d = dst[i];
        uint slot = atomicAdd(&cur[d >> 8], 1u);
        rec[slot] = ((uint)(d & 255) << 24) | (uint)src[i];
    }
}

__global__ __launch_bounds__(256) void bucket_build(
        const uint* __restrict__ scn, const uint* __restrict__ rec,
        int* __restrict__ rp, int* __restrict__ adj,
        float* __restrict__ dinv, int E, int NB, int n) {
    __shared__ uint cnt[256];
    __shared__ uint sc[2][256];
    int b = blockIdx.x, t = threadIdx.x;
    uint base = scn[(size_t)b * CS_G];
    uint bend = (b + 1 < NB) ? scn[(size_t)(b + 1) * CS_G] : (uint)E;
    cnt[t] = 0;
    __syncthreads();
    for (uint i = base + t; i < bend; i += 256)
        atomicAdd(&cnt[rec[i] >> 24], 1u);
    __syncthreads();
    uint vcnt = cnt[t];
    sc[0][t] = vcnt;
    __syncthreads();
    int pb = 0;
    for (int off = 1; off < 256; off <<= 1) {
        uint add = (t >= off) ? sc[pb][t - off] : 0u;
        sc[pb ^ 1][t] = sc[pb][t] + add;
        pb ^= 1;
        __syncthreads();
    }
    uint excl = sc[pb][t] - vcnt;
    uint off0 = base + excl;
    int vtx = b * 256 + t;
    if (vtx < n) {
        rp[vtx] = (int)off0;
        dinv[vtx] = rsqrtf((float)(vcnt + 1));
    }
    if (b == 0 && t == 0) rp[n] = E;
    cnt[t] = off0;   // repurpose as cursor
    __syncthreads();
    for (uint i = base + t; i < bend; i += 256) {
        uint r = rec[i];
        uint slot = atomicAdd(&cnt[r >> 24], 1u);
        adj[slot] = (int)(r & 0xFFFFFFu);
    }
}

// tw[src] += dinv[dst]
__global__ void tw_kernel(const int* __restrict__ src, const int* __restrict__ dst,
                          const float* __restrict__ dinv, float* __restrict__ tw, int E) {
    int i = blockIdx.x * blockDim.x + threadIdx.x;
    int e = i * 4;
    if (e + 4 <= E) {
        int4 s = *(const int4*)(src + e);
        int4 d = *(const int4*)(dst + e);
        atomicAdd(&tw[s.x], dinv[d.x]);
        atomicAdd(&tw[s.y], dinv[d.y]);
        atomicAdd(&tw[s.z], dinv[d.z]);
        atomicAdd(&tw[s.w], dinv[d.w]);
    } else {
        for (; e < E; ++e) atomicAdd(&tw[src[e]], dinv[dst[e]]);
    }
}

// ================= scan machinery (reused for counts array) =================

#define SC_T 256
#define SC_C 1024

__global__ void scan_part(const int* __restrict__ deg, int* __restrict__ bsum, int n) {
    __shared__ int sh[SC_T];
    int t = threadIdx.x;
    int base = blockIdx.x * SC_C;
    int s = 0;
    for (int i = 0; i < 4; i++) {
        int idx = base + t * 4 + i;
        if (idx < n) s += deg[idx];
    }
    sh[t] = s;
    __syncthreads();
    for (int off = 128; off > 0; off >>= 1) {
        if (t < off) sh[t] += sh[t + off];
        __syncthreads();
    }
    if (t == 0) bsum[blockIdx.x] = sh[0];
}

__global__ void scan_bsums(int* bsum, int nb, int* total) {
    if (threadIdx.x == 0 && blockIdx.x == 0) {
        int acc = 0;
        for (int i = 0; i < nb; i++) { int v = bsum[i]; bsum[i] = acc; acc += v; }
        *total = acc;
    }
}

__global__ void scan_write(const int* __restrict__ deg, const int* __restrict__ bsum,
                           const int* __restrict__ total, int* __restrict__ rp, int n) {
    __shared__ int sh[SC_T];
    int t = threadIdx.x;
    int base = blockIdx.x * SC_C;
    int vals[4];
    int s = 0;
    for (int i = 0; i < 4; i++) {
        int idx = base + t * 4 + i;
        vals[i] = (idx < n) ? deg[idx] : 0;
        s += vals[i];
    }
    sh[t] = s;
    __syncthreads();
    for (int off = 1; off < SC_T; off <<= 1) {
        int v = (t >= off) ? sh[t - off] : 0;
        __syncthreads();
        sh[t] += v;
        __syncthreads();
    }
    int excl = sh[t] - s + bsum[blockIdx.x];
    for (int i = 0; i < 4; i++) {
        int idx = base + t * 4 + i;
        if (idx < n) { rp[idx] = excl; excl += vals[i]; }
    }
    if (blockIdx.x == 0 && t == 0) rp[n] = *total;
}

// ================= W1 pre-pack into MFMA B-fragment layout =================
// Wp[((kc*8 + n)*64 + lane)*8 + j] = W[kc*32 + (lane>>4)*8 + j][n*16 + (lane&15)]

__global__ void pack_w(const float* __restrict__ W, ushort* __restrict__ Wp) {
    int kc = blockIdx.x >> 3, n = blockIdx.x & 7;
    int l = threadIdx.x;
    ushort o[8];
#pragma unroll
    for (int j = 0; j < 8; ++j) {
        float v = W[(size_t)(kc * 32 + ((l >> 4) * 8) + j) * 128 + n * 16 + (l & 15)];
        o[j] = f2bf(v);
    }
    uint4 pk;
    pk.x = (uint)o[0] | ((uint)o[1] << 16);
    pk.y = (uint)o[2] | ((uint)o[3] << 16);
    pk.z = (uint)o[4] | ((uint)o[5] << 16);
    pk.w = (uint)o[6] | ((uint)o[7] << 16);
    *(uint4*)(Wp + ((size_t)(kc * 8 + n) * 64 + l) * 8) = pk;
}

// ================= GEMM1: Cb[M,128](bf16) = X[M,K](fp32) @ W1 (packed) =================

__global__ __launch_bounds__(256) void gemm1_mfma(
        const float* __restrict__ X, const ushort* __restrict__ Wp,
        ushort* __restrict__ Cb, int M, int K) {
    __shared__ ushort As[2][64][40];
    int t = threadIdx.x, lane = t & 63, w = t >> 6;
    int brow = blockIdx.x * 64;
    int KC = K >> 5;
    f32x4 acc[8] = {};
    int sr = t >> 2, sk = (t & 3) * 8;
    int gr = brow + sr;
    bool xok = gr < M;
    int frow = w * 16 + (lane & 15);
    int fk = (lane >> 4) * 8;

    auto loadpk = [&](int kc) -> uint4 {
        float4 xa = make_float4(0.f, 0.f, 0.f, 0.f), xb = xa;
        if (xok) {
            const float* xp = X + (size_t)gr * K + kc * 32 + sk;
            xa = *(const float4*)xp;
            xb = *(const float4*)(xp + 4);
        }
        uint4 pk;
        pk.x = pk2(xa.x, xa.y);
        pk.y = pk2(xa.z, xa.w);
        pk.z = pk2(xb.x, xb.y);
        pk.w = pk2(xb.z, xb.w);
        return pk;
    };

    uint4 cur = loadpk(0);
    int buf = 0;
    for (int kc = 0; kc < KC; ++kc) {
        *(uint4*)&As[buf][sr][sk] = cur;
        __syncthreads();
        if (kc + 1 < KC) cur = loadpk(kc + 1);
        bf16x8 af = *(const bf16x8*)&As[buf][frow][fk];
        const ushort* wbase = Wp + ((size_t)(kc * 8) * 64 + lane) * 8;
#pragma unroll
        for (int n = 0; n < 8; ++n) {
            bf16x8 bfr = *(const bf16x8*)(wbase + (size_t)n * 64 * 8);
            acc[n] = __builtin_amdgcn_mfma_f32_16x16x32_bf16(af, bfr, acc[n], 0, 0, 0);
        }
        buf ^= 1;
    }
    int colbase = lane & 15;
    int rowbase = brow + w * 16 + ((lane >> 4) << 2);
#pragma unroll
    for (int n = 0; n < 8; ++n) {
#pragma unroll
        for (int r = 0; r < 4; ++r) {
            int grr = rowbase + r;
            if (grr < M) Cb[(size_t)grr * 128 + n * 16 + colbase] = f2bf(acc[n][r]);
        }
    }
}

// ================= layer-1 dual propagation: 4 nodes/wave, 16B gathers =================

#define ACC8(acc, g, w)                                   \
    acc[0] += bflo(g.x) * w; acc[1] += bfhi(g.x) * w;     \
    acc[2] += bflo(g.y) * w; acc[3] += bfhi(g.y) * w;     \
    acc[4] += bflo(g.z) * w; acc[5] += bfhi(g.z) * w;     \
    acc[6] += bflo(g.w) * w; acc[7] += bfhi(g.w) * w;

__global__ __launch_bounds__(256) void prop4_l1(
        const ushort* __restrict__ P0,
        const int* __restrict__ rp, const int* __restrict__ adj,
        const float* __restrict__ dinv, const int* __restrict__ perm,
        const float* __restrict__ bias,
        ushort* __restrict__ O0, ushort* __restrict__ O1, int n) {
    int wave = (blockIdx.x * blockDim.x + threadIdx.x) >> 6;
    int lane = threadIdx.x & 63;
    int q = lane >> 4, l = lane & 15;
    int v = wave * 4 + q;
    bool vok = v < n;
    int vc = vok ? v : (n - 1);
    float dv = dinv[vc];
    int s1 = perm[vc];

    uint4 r0 = *(const uint4*)(P0 + (size_t)vc * 128 + 8 * l);
    uint4 r1 = *(const uint4*)(P0 + (size_t)s1 * 128 + 8 * l);
    float a0[8], a1[8];
    a0[0] = bflo(r0.x) * dv; a0[1] = bfhi(r0.x) * dv;
    a0[2] = bflo(r0.y) * dv; a0[3] = bfhi(r0.y) * dv;
    a0[4] = bflo(r0.z) * dv; a0[5] = bfhi(r0.z) * dv;
    a0[6] = bflo(r0.w) * dv; a0[7] = bfhi(r0.w) * dv;
    a1[0] = bflo(r1.x) * dv; a1[1] = bfhi(r1.x) * dv;
    a1[2] = bflo(r1.y) * dv; a1[3] = bfhi(r1.y) * dv;
    a1[4] = bflo(r1.z) * dv; a1[5] = bfhi(r1.z) * dv;
    a1[6] = bflo(r1.w) * dv; a1[7] = bfhi(r1.w) * dv;

    int i = rp[vc], end = rp[vc + 1];
    int un[4];
#pragma unroll
    for (int k = 0; k < 4; ++k) un[k] = (i + k < end) ? adj[i + k] : vc;

    while (__ballot(i < end)) {
        int uc[4];
#pragma unroll
        for (int k = 0; k < 4; ++k) uc[k] = un[k];
        uint4 g0[4];
#pragma unroll
        for (int k = 0; k < 4; ++k) g0[k] = *(const uint4*)(P0 + (size_t)uc[k] * 128 + 8 * l);
        int uu[4];
#pragma unroll
        for (int k = 0; k < 4; ++k) uu[k] = perm[uc[k]];
        uint4 g1[4];
#pragma unroll
        for (int k = 0; k < 4; ++k) g1[k] = *(const uint4*)(P0 + (size_t)uu[k] * 128 + 8 * l);
        float du[4];
#pragma unroll
        for (int k = 0; k < 4; ++k) du[k] = (i + k < end) ? dinv[uc[k]] : 0.f;
        i += 4;
#pragma unroll
        for (int k = 0; k < 4; ++k) un[k] = (i + k < end) ? adj[i + k] : vc;
#pragma unroll
        for (int k = 0; k < 4; ++k) {
            float w = du[k];
            ACC8(a0, g0[k], w)
            ACC8(a1, g1[k], w)
        }
    }
    if (!vok) return;
    float4 bA = *(const float4*)(bias + 8 * l);
    float4 bB = *(const float4*)(bias + 8 * l + 4);
    float bb[8] = {bA.x, bA.y, bA.z, bA.w, bB.x, bB.y, bB.z, bB.w};
#pragma unroll
    for (int j = 0; j < 8; ++j) {
        a0[j] = fmaxf(a0[j] * dv + bb[j], 0.f);
        a1[j] = fmaxf(a1[j] * dv + bb[j], 0.f);
    }
    uint4 o;
    o.x = pk2(a0[0], a0[1]); o.y = pk2(a0[2], a0[3]);
    o.z = pk2(a0[4], a0[5]); o.w = pk2(a0[6], a0[7]);
    *(uint4*)(O0 + (size_t)v * 128 + 8 * l) = o;
    o.x = pk2(a1[0], a1[1]); o.y = pk2(a1[2], a1[3]);
    o.z = pk2(a1[4], a1[5]); o.w = pk2(a1[6], a1[7]);
    *(uint4*)(O1 + (size_t)v * 128 + 8 * l) = o;
}

// ================= readout chain =================

__global__ __launch_bounds__(256) void wcolsum(
        const ushort* __restrict__ B, const float* __restrict__ tw,
        const float* __restrict__ dinv, float* __restrict__ mBvec, int n) {
    __shared__ float sh[4][128];
    int t = threadIdx.x;
    int cp = t & 63;
    int rg = t >> 6;
    int r0 = blockIdx.x * 512;
    int r1 = min(r0 + 512, n);
    float acc0 = 0.f, acc1 = 0.f;
    for (int r = r0 + rg; r < r1; r += 4) {
        float tv = dinv[r] * (tw[r] + dinv[r]);
        uint b = *(const uint*)(B + (size_t)r * 128 + 2 * cp);
        acc0 += bflo(b) * tv;
        acc1 += bfhi(b) * tv;
    }
    sh[rg][2 * cp] = acc0;
    sh[rg][2 * cp + 1] = acc1;
    __syncthreads();
    if (t < 128) {
        float s = sh[0][t] + sh[1][t] + sh[2][t] + sh[3][t];
        atomicAdd(&mBvec[t], s);
    }
}

__global__ void tiny_chain(const float* __restrict__ mBvec, const float* __restrict__ W2,
                           const float* __restrict__ b2, const float* __restrict__ Wd,
                           const float* __restrict__ bd,
                           float* __restrict__ w2s, float* __restrict__ k0, int n) {
    __shared__ float s_sh[128];
    __shared__ float ws_sh[128];
    __shared__ float red[128];
    int t = threadIdx.x;
    float acc = 0.f;
    for (int k = 0; k < 128; ++k) acc += mBvec[k] * W2[k * 128 + t];
    float m = acc / (float)n + b2[t];
    s_sh[t] = 1.f / (1.f + expf(-m));
    __syncthreads();
    acc = 0.f;
    for (int j = 0; j < 128; ++j) acc += Wd[t * 128 + j] * s_sh[j];
    ws_sh[t] = acc;
    __syncthreads();
    acc = 0.f;
    for (int j = 0; j < 128; ++j) acc += W2[t * 128 + j] * ws_sh[j];
    w2s[t] = acc;
    red[t] = b2[t] * ws_sh[t];
    __syncthreads();
    for (int off = 64; off > 0; off >>= 1) {
        if (t < off) red[t] += red[t + off];
        __syncthreads();
    }
    if (t == 0) *k0 = red[0] + bd[0];
}

__global__ __launch_bounds__(256) void cdot(
        const ushort* __restrict__ B, const ushort* __restrict__ B2,
        const float* __restrict__ w2s, const float* __restrict__ dinv,
        float* __restrict__ c0p, float* __restrict__ c1p, int n) {
    int wave = (blockIdx.x * blockDim.x + threadIdx.x) >> 6;
    int lane = threadIdx.x & 63;
    if (wave >= n) return;
    float w0 = w2s[2 * lane], w1 = w2s[2 * lane + 1];
    uint b = *(const uint*)(B + (size_t)wave * 128 + 2 * lane);
    uint c = *(const uint*)(B2 + (size_t)wave * 128 + 2 * lane);
    float a = bflo(b) * w0 + bfhi(b) * w1;
    float d = bflo(c) * w0 + bfhi(c) * w1;
#pragma unroll
    for (int off = 32; off > 0; off >>= 1) {
        a += __shfl_xor(a, off);
        d += __shfl_xor(d, off);
    }
    if (lane == 0) {
        float dv = dinv[wave];
        c0p[wave] = dv * a;
        c1p[wave] = dv * d;
    }
}

__global__ __launch_bounds__(256) void sprop(
        const float* __restrict__ c0p, const float* __restrict__ c1p,
        const int* __restrict__ rp, const int* __restrict__ adj,
        const float* __restrict__ dinv, const float* __restrict__ k0,
        float* __restrict__ out, int n) {
    int wave = (blockIdx.x * blockDim.x + threadIdx.x) >> 6;
    int lane = threadIdx.x & 63;
    int q = lane >> 4, l = lane & 15;
    int v = wave * 4 + q;
    if (v >= n) return;
    float a0 = 0.f, a1 = 0.f;
    int beg = rp[v], end = rp[v + 1];
    for (int i = beg + l; i < end; i += 16) {
        int u = adj[i];
        a0 += c0p[u];
        a1 += c1p[u];
    }
#pragma unroll
    for (int off = 1; off < 16; off <<= 1) {
        a0 += __shfl_xor(a0, off);
        a1 += __shfl_xor(a1, off);
    }
    if (l == 0) {
        float dv = dinv[v];
        float kk = *k0;
        out[v] = dv * (a0 + c0p[v]) + kk;
        out[n + v] = dv * (a1 + c1p[v]) + kk;
    }
}

// ================= launch =================

extern "C" void kernel_launch(void* const* d_in, const int* in_sizes, int n_in,
                              void* d_out, int out_size, void* d_ws, size_t ws_size,
                              hipStream_t stream) {
    const float* x  = (const float*)d_in[0];
    const int*   ei = (const int*)d_in[1];
    const int* perm = (const int*)d_in[2];
    const float* W1 = (const float*)d_in[3];
    const float* b1 = (const float*)d_in[4];
    const float* W2 = (const float*)d_in[5];
    const float* b2 = (const float*)d_in[6];
    const float* Wd = (const float*)d_in[7];
    const float* bd = (const float*)d_in[8];

    const int N = in_sizes[2];
    const int E = in_sizes[1] / 2;
    const int IN = in_sizes[0] / N;  // 512
    const int* src = ei;
    const int* dst = ei + E;
    float* out = (float*)d_out;

    const int NB = (N + 255) >> 8;          // buckets (256 nodes each), <= 512
    const int M_CNT = NB * CS_G;            // counts array size
    const int chunk = (E + CS_G - 1) / CS_G;

    char* p = (char*)d_ws;
    auto alloc = [&](size_t bytes) -> void* {
        void* r = (void*)p;
        p += (bytes + 511) & ~(size_t)511;
        return r;
    };
    // zero-init group (contiguous, single memset)
    float* tw     = (float*)alloc((size_t)N * 4);
    float* mBvec  = (float*)alloc(512);
    size_t zspan = (size_t)((char*)p - (char*)tw);
    // rest
    uint*  counts = (uint*)alloc((size_t)M_CNT * 4);
    uint*  scn    = (uint*)alloc((size_t)(M_CNT + 1) * 4);
    uint*  rec    = (uint*)alloc((size_t)E * 4);
    int*   rp     = (int*)alloc((size_t)(N + 1) * 4);
    int*   adj    = (int*)alloc((size_t)E * 4);
    float* dinv   = (float*)alloc((size_t)N * 4);
    int*   bsum   = (int*)alloc(4096);
    int*   total  = (int*)alloc(64);
    float* w2sv   = (float*)alloc(512);
    float* k0v    = (float*)alloc(64);
    float* c0p    = (float*)alloc((size_t)N * 4);
    float* c1p    = (float*)alloc((size_t)N * 4);
    ushort* W1p   = (ushort*)alloc((size_t)512 * 128 * 2);
    ushort* A  = (ushort*)alloc((size_t)N * 128 * 2);
    ushort* B  = (ushort*)alloc((size_t)N * 128 * 2);
    ushort* B2 = (ushort*)alloc((size_t)N * 128 * 2);

    hipMemsetAsync(tw, 0, zspan, stream);

    // --- CSR build (counting sort) ---
    part_hist<<<CS_G, 256, 0, stream>>>(dst, counts, E, NB, chunk);
    int nb_sc = (M_CNT + SC_C - 1) / SC_C;
    scan_part<<<nb_sc, SC_T, 0, stream>>>((const int*)counts, bsum, M_CNT);
    scan_bsums<<<1, 1, 0, stream>>>(bsum, nb_sc, total);
    scan_write<<<nb_sc, SC_T, 0, stream>>>((const int*)counts, bsum, total, (int*)scn, M_CNT);
    part_scatter<<<CS_G, 256, 0, stream>>>(src, dst, scn, rec, E, NB, chunk);
    bucket_build<<<NB, 256, 0, stream>>>(scn, rec, rp, adj, dinv, E, NB, N);
    tw_kernel<<<(E / 4 + 255) / 256, 256, 0, stream>>>(src, dst, dinv, tw, E);

    // --- dense pipeline ---
    pack_w<<<(IN / 32) * 8, 64, 0, stream>>>(W1, W1p);

    int gemm_blocks = (N + 63) / 64;
    int p4_blocks = ((N + 3) / 4 + 3) / 4;

    gemm1_mfma<<<gemm_blocks, 256, 0, stream>>>(x, W1p, A, N, IN);
    prop4_l1<<<p4_blocks, 256, 0, stream>>>(A, rp, adj, dinv, perm, b1, B, B2, N);
    wcolsum<<<(N + 511) / 512, 256, 0, stream>>>(B, tw, dinv, mBvec, N);
    tiny_chain<<<1, 128, 0, stream>>>(mBvec, W2, b2, Wd, bd, w2sv, k0v, N);
    cdot<<<(N + 3) / 4, 256, 0, stream>>>(B, B2, w2sv, dinv, c0p, c1p, N);
    sprop<<<p4_blocks, 256, 0, stream>>>(c0p, c1p, rp, adj, dinv, k0v, out, N);
}

// Round 6
// 640.912 us; speedup vs baseline: 3.5750x; 1.0994x over previous
//
#include <hip/hip_runtime.h>
#include <hip/hip_bf16.h>

typedef unsigned int uint;
typedef unsigned short ushort;
typedef __attribute__((ext_vector_type(8))) short bf16x8;
typedef __attribute__((ext_vector_type(4))) float f32x4;

static __device__ __forceinline__ ushort f2bf(float f) {
    uint u = __builtin_bit_cast(uint, f);
    return (ushort)((u + 0x7FFFu + ((u >> 16) & 1u)) >> 16);
}
static __device__ __forceinline__ uint pk2(float lo, float hi) {
    return (uint)f2bf(lo) | ((uint)f2bf(hi) << 16);
}
static __device__ __forceinline__ float bflo(uint u) { return __builtin_bit_cast(float, u << 16); }
static __device__ __forceinline__ float bfhi(uint u) { return __builtin_bit_cast(float, u & 0xFFFF0000u); }

// ================= CSR build via two-level counting sort =================
// bucket = dst >> 8 (256 nodes per bucket). NB <= 512 (N <= 131072).

#define CS_G 512   // partition grid

__global__ __launch_bounds__(256) void part_hist(
        const int* __restrict__ dst, uint* __restrict__ counts,
        int E, int NB, int chunk) {
    __shared__ uint h[512];
    int t = threadIdx.x;
    for (int b = t; b < NB; b += 256) h[b] = 0;
    __syncthreads();
    int s0 = blockIdx.x * chunk;
    int s1 = min(s0 + chunk, E);
    for (int i = s0 + t; i < s1; i += 256) {
        atomicAdd(&h[dst[i] >> 8], 1u);
    }
    __syncthreads();
    for (int b = t; b < NB; b += 256)
        counts[(size_t)b * CS_G + blockIdx.x] = h[b];
}

__global__ __launch_bounds__(256) void part_scatter(
        const int* __restrict__ src, const int* __restrict__ dst,
        const uint* __restrict__ scn, uint* __restrict__ rec,
        int E, int NB, int chunk) {
    __shared__ uint cur[512];
    int t = threadIdx.x;
    for (int b = t; b < NB; b += 256) cur[b] = scn[(size_t)b * CS_G + blockIdx.x];
    __syncthreads();
    int s0 = blockIdx.x * chunk;
    int s1 = min(s0 + chunk, E);
    for (int i = s0 + t; i < s1; i += 256) {
        int d = dst[i];
        uint slot = atomicAdd(&cur[d >> 8], 1u);
        rec[slot] = ((uint)(d & 255) << 24) | (uint)src[i];
    }
}

// per bucket: per-node counts -> rp, dinv; scatter adj; accumulate tw[src] += dinv[dst]
__global__ __launch_bounds__(256) void bucket_build(
        const uint* __restrict__ scn, const uint* __restrict__ rec,
        int* __restrict__ rp, int* __restrict__ adj,
        float* __restrict__ dinv, float* __restrict__ tw,
        int E, int NB, int n) {
    __shared__ uint cnt[256];
    __shared__ uint sc[2][256];
    __shared__ float dsh[256];
    int b = blockIdx.x, t = threadIdx.x;
    uint base = scn[(size_t)b * CS_G];
    uint bend = (b + 1 < NB) ? scn[(size_t)(b + 1) * CS_G] : (uint)E;
    cnt[t] = 0;
    __syncthreads();
    for (uint i = base + t; i < bend; i += 256)
        atomicAdd(&cnt[rec[i] >> 24], 1u);
    __syncthreads();
    uint vcnt = cnt[t];
    float dv = rsqrtf((float)(vcnt + 1));
    dsh[t] = dv;
    sc[0][t] = vcnt;
    __syncthreads();
    int pb = 0;
    for (int off = 1; off < 256; off <<= 1) {
        uint add = (t >= off) ? sc[pb][t - off] : 0u;
        sc[pb ^ 1][t] = sc[pb][t] + add;
        pb ^= 1;
        __syncthreads();
    }
    uint excl = sc[pb][t] - vcnt;
    uint off0 = base + excl;
    int vtx = b * 256 + t;
    if (vtx < n) {
        rp[vtx] = (int)off0;
        dinv[vtx] = dv;
    }
    if (b == 0 && t == 0) rp[n] = E;
    cnt[t] = off0;   // repurpose as cursor
    __syncthreads();
    for (uint i = base + t; i < bend; i += 256) {
        uint r = rec[i];
        uint dloc = r >> 24;
        uint s = r & 0xFFFFFFu;
        uint slot = atomicAdd(&cnt[dloc], 1u);
        adj[slot] = (int)s;
        atomicAdd(&tw[s], dsh[dloc]);
    }
}

// ================= scan machinery =================

#define SC_T 256
#define SC_C 1024

__global__ void scan_part(const int* __restrict__ deg, int* __restrict__ bsum, int n) {
    __shared__ int sh[SC_T];
    int t = threadIdx.x;
    int base = blockIdx.x * SC_C;
    int s = 0;
    for (int i = 0; i < 4; i++) {
        int idx = base + t * 4 + i;
        if (idx < n) s += deg[idx];
    }
    sh[t] = s;
    __syncthreads();
    for (int off = 128; off > 0; off >>= 1) {
        if (t < off) sh[t] += sh[t + off];
        __syncthreads();
    }
    if (t == 0) bsum[blockIdx.x] = sh[0];
}

// parallel exclusive scan of nb (<=256) block sums, one block
__global__ void scan_block(int* bsum, int nb, int* total) {
    __shared__ int sh[256];
    int t = threadIdx.x;
    int v = (t < nb) ? bsum[t] : 0;
    sh[t] = v;
    __syncthreads();
    for (int off = 1; off < 256; off <<= 1) {
        int u = (t >= off) ? sh[t - off] : 0;
        __syncthreads();
        sh[t] += u;
        __syncthreads();
    }
    if (t < nb) bsum[t] = sh[t] - v;
    if (t == 0) *total = sh[255];
}

__global__ void scan_write(const int* __restrict__ deg, const int* __restrict__ bsum,
                           const int* __restrict__ total, int* __restrict__ rp, int n) {
    __shared__ int sh[SC_T];
    int t = threadIdx.x;
    int base = blockIdx.x * SC_C;
    int vals[4];
    int s = 0;
    for (int i = 0; i < 4; i++) {
        int idx = base + t * 4 + i;
        vals[i] = (idx < n) ? deg[idx] : 0;
        s += vals[i];
    }
    sh[t] = s;
    __syncthreads();
    for (int off = 1; off < SC_T; off <<= 1) {
        int v = (t >= off) ? sh[t - off] : 0;
        __syncthreads();
        sh[t] += v;
        __syncthreads();
    }
    int excl = sh[t] - s + bsum[blockIdx.x];
    for (int i = 0; i < 4; i++) {
        int idx = base + t * 4 + i;
        if (idx < n) { rp[idx] = excl; excl += vals[i]; }
    }
    if (blockIdx.x == 0 && t == 0) rp[n] = *total;
}

// ================= W1 pre-pack into MFMA B-fragment layout =================

__global__ void pack_w(const float* __restrict__ W, ushort* __restrict__ Wp) {
    int kc = blockIdx.x >> 3, n = blockIdx.x & 7;
    int l = threadIdx.x;
    ushort o[8];
#pragma unroll
    for (int j = 0; j < 8; ++j) {
        float v = W[(size_t)(kc * 32 + ((l >> 4) * 8) + j) * 128 + n * 16 + (l & 15)];
        o[j] = f2bf(v);
    }
    uint4 pk;
    pk.x = (uint)o[0] | ((uint)o[1] << 16);
    pk.y = (uint)o[2] | ((uint)o[3] << 16);
    pk.z = (uint)o[4] | ((uint)o[5] << 16);
    pk.w = (uint)o[6] | ((uint)o[7] << 16);
    *(uint4*)(Wp + ((size_t)(kc * 8 + n) * 64 + l) * 8) = pk;
}

// ================= GEMM1: Cb[M,128](bf16) = X[M,K](fp32) @ W1 (packed) =================

__global__ __launch_bounds__(256) void gemm1_mfma(
        const float* __restrict__ X, const ushort* __restrict__ Wp,
        ushort* __restrict__ Cb, int M, int K) {
    __shared__ ushort As[2][64][40];
    int t = threadIdx.x, lane = t & 63, w = t >> 6;
    int brow = blockIdx.x * 64;
    int KC = K >> 5;
    f32x4 acc[8] = {};
    int sr = t >> 2, sk = (t & 3) * 8;
    int gr = brow + sr;
    bool xok = gr < M;
    int frow = w * 16 + (lane & 15);
    int fk = (lane >> 4) * 8;

    auto loadpk = [&](int kc) -> uint4 {
        float4 xa = make_float4(0.f, 0.f, 0.f, 0.f), xb = xa;
        if (xok) {
            const float* xp = X + (size_t)gr * K + kc * 32 + sk;
            xa = *(const float4*)xp;
            xb = *(const float4*)(xp + 4);
        }
        uint4 pk;
        pk.x = pk2(xa.x, xa.y);
        pk.y = pk2(xa.z, xa.w);
        pk.z = pk2(xb.x, xb.y);
        pk.w = pk2(xb.z, xb.w);
        return pk;
    };

    uint4 cur = loadpk(0);
    int buf = 0;
    for (int kc = 0; kc < KC; ++kc) {
        *(uint4*)&As[buf][sr][sk] = cur;
        __syncthreads();
        if (kc + 1 < KC) cur = loadpk(kc + 1);
        bf16x8 af = *(const bf16x8*)&As[buf][frow][fk];
        const ushort* wbase = Wp + ((size_t)(kc * 8) * 64 + lane) * 8;
#pragma unroll
        for (int n = 0; n < 8; ++n) {
            bf16x8 bfr = *(const bf16x8*)(wbase + (size_t)n * 64 * 8);
            acc[n] = __builtin_amdgcn_mfma_f32_16x16x32_bf16(af, bfr, acc[n], 0, 0, 0);
        }
        buf ^= 1;
    }
    int colbase = lane & 15;
    int rowbase = brow + w * 16 + ((lane >> 4) << 2);
#pragma unroll
    for (int n = 0; n < 8; ++n) {
#pragma unroll
        for (int r = 0; r < 4; ++r) {
            int grr = rowbase + r;
            if (grr < M) Cb[(size_t)grr * 128 + n * 16 + colbase] = f2bf(acc[n][r]);
        }
    }
}

// ================= layer-1 propagation, branch 0: B = relu(S*A + b1) =================

#define ACC8(acc, g, w)                                   \
    acc[0] += bflo(g.x) * w; acc[1] += bfhi(g.x) * w;     \
    acc[2] += bflo(g.y) * w; acc[3] += bfhi(g.y) * w;     \
    acc[4] += bflo(g.z) * w; acc[5] += bfhi(g.z) * w;     \
    acc[6] += bflo(g.w) * w; acc[7] += bfhi(g.w) * w;

__global__ __launch_bounds__(256) void prop_b0(
        const ushort* __restrict__ A,
        const int* __restrict__ rp, const int* __restrict__ adj,
        const float* __restrict__ dinv, const float* __restrict__ bias,
        ushort* __restrict__ B, int n) {
    int wave = (blockIdx.x * blockDim.x + threadIdx.x) >> 6;
    int lane = threadIdx.x & 63;
    int q = lane >> 4, l = lane & 15;
    int v = wave * 4 + q;
    bool vok = v < n;
    int vc = vok ? v : (n - 1);
    float dv = dinv[vc];

    uint4 r0 = *(const uint4*)(A + (size_t)vc * 128 + 8 * l);
    float a0[8];
    a0[0] = bflo(r0.x) * dv; a0[1] = bfhi(r0.x) * dv;
    a0[2] = bflo(r0.y) * dv; a0[3] = bfhi(r0.y) * dv;
    a0[4] = bflo(r0.z) * dv; a0[5] = bfhi(r0.z) * dv;
    a0[6] = bflo(r0.w) * dv; a0[7] = bfhi(r0.w) * dv;

    int i = rp[vc], end = rp[vc + 1];
    int un[4];
#pragma unroll
    for (int k = 0; k < 4; ++k) un[k] = (i + k < end) ? adj[i + k] : vc;

    while (__ballot(i < end)) {
        int uc[4];
#pragma unroll
        for (int k = 0; k < 4; ++k) uc[k] = un[k];
        uint4 g0[4];
#pragma unroll
        for (int k = 0; k < 4; ++k) g0[k] = *(const uint4*)(A + (size_t)uc[k] * 128 + 8 * l);
        float du[4];
#pragma unroll
        for (int k = 0; k < 4; ++k) du[k] = (i + k < end) ? dinv[uc[k]] : 0.f;
        i += 4;
#pragma unroll
        for (int k = 0; k < 4; ++k) un[k] = (i + k < end) ? adj[i + k] : vc;
#pragma unroll
        for (int k = 0; k < 4; ++k) {
            float w = du[k];
            ACC8(a0, g0[k], w)
        }
    }
    if (!vok) return;
    float4 bA = *(const float4*)(bias + 8 * l);
    float4 bB = *(const float4*)(bias + 8 * l + 4);
    float bb[8] = {bA.x, bA.y, bA.z, bA.w, bB.x, bB.y, bB.z, bB.w};
#pragma unroll
    for (int j = 0; j < 8; ++j)
        a0[j] = fmaxf(a0[j] * dv + bb[j], 0.f);
    uint4 o;
    o.x = pk2(a0[0], a0[1]); o.y = pk2(a0[2], a0[3]);
    o.z = pk2(a0[4], a0[5]); o.w = pk2(a0[6], a0[7]);
    *(uint4*)(B + (size_t)v * 128 + 8 * l) = o;
}

// ================= branch 1 + fused dots: cpair[v] = (dv*B[v].w2s, dv*relu(S_perm*A+b1)[v].w2s) =================

__global__ __launch_bounds__(256) void prop_b1(
        const ushort* __restrict__ A, const ushort* __restrict__ B,
        const int* __restrict__ rp, const int* __restrict__ adj,
        const float* __restrict__ dinv, const int* __restrict__ perm,
        const float* __restrict__ bias, const float* __restrict__ w2s,
        float2* __restrict__ cpair, int n) {
    int wave = (blockIdx.x * blockDim.x + threadIdx.x) >> 6;
    int lane = threadIdx.x & 63;
    int q = lane >> 4, l = lane & 15;
    int v = wave * 4 + q;
    bool vok = v < n;
    int vc = vok ? v : (n - 1);
    float dv = dinv[vc];
    int self = perm[vc];

    uint4 r1 = *(const uint4*)(A + (size_t)self * 128 + 8 * l);
    float a1[8];
    a1[0] = bflo(r1.x) * dv; a1[1] = bfhi(r1.x) * dv;
    a1[2] = bflo(r1.y) * dv; a1[3] = bfhi(r1.y) * dv;
    a1[4] = bflo(r1.z) * dv; a1[5] = bfhi(r1.z) * dv;
    a1[6] = bflo(r1.w) * dv; a1[7] = bfhi(r1.w) * dv;

    int i = rp[vc], end = rp[vc + 1];
    int un[4];
#pragma unroll
    for (int k = 0; k < 4; ++k) un[k] = (i + k < end) ? adj[i + k] : vc;

    while (__ballot(i < end)) {
        int uc[4];
#pragma unroll
        for (int k = 0; k < 4; ++k) uc[k] = un[k];
        int uu[4];
#pragma unroll
        for (int k = 0; k < 4; ++k) uu[k] = perm[uc[k]];
        uint4 g1[4];
#pragma unroll
        for (int k = 0; k < 4; ++k) g1[k] = *(const uint4*)(A + (size_t)uu[k] * 128 + 8 * l);
        float du[4];
#pragma unroll
        for (int k = 0; k < 4; ++k) du[k] = (i + k < end) ? dinv[uc[k]] : 0.f;
        i += 4;
#pragma unroll
        for (int k = 0; k < 4; ++k) un[k] = (i + k < end) ? adj[i + k] : vc;
#pragma unroll
        for (int k = 0; k < 4; ++k) {
            float w = du[k];
            ACC8(a1, g1[k], w)
        }
    }
    if (!vok) return;
    float4 bA = *(const float4*)(bias + 8 * l);
    float4 bB = *(const float4*)(bias + 8 * l + 4);
    float bb[8] = {bA.x, bA.y, bA.z, bA.w, bB.x, bB.y, bB.z, bB.w};
    float4 wA = *(const float4*)(w2s + 8 * l);
    float4 wB = *(const float4*)(w2s + 8 * l + 4);
    float ww[8] = {wA.x, wA.y, wA.z, wA.w, wB.x, wB.y, wB.z, wB.w};
    // c1 = relu branch-1 row . w2s
    float c1 = 0.f;
#pragma unroll
    for (int j = 0; j < 8; ++j)
        c1 += fmaxf(a1[j] * dv + bb[j], 0.f) * ww[j];
    // c0 = B[v] . w2s
    uint4 b0 = *(const uint4*)(B + (size_t)vc * 128 + 8 * l);
    float c0 = bflo(b0.x) * ww[0] + bfhi(b0.x) * ww[1]
             + bflo(b0.y) * ww[2] + bfhi(b0.y) * ww[3]
             + bflo(b0.z) * ww[4] + bfhi(b0.z) * ww[5]
             + bflo(b0.w) * ww[6] + bfhi(b0.w) * ww[7];
#pragma unroll
    for (int off = 1; off < 16; off <<= 1) {
        c0 += __shfl_xor(c0, off);
        c1 += __shfl_xor(c1, off);
    }
    if (l == 0) cpair[v] = make_float2(dv * c0, dv * c1);
}

// ================= readout chain =================

__global__ __launch_bounds__(256) void wcolsum(
        const ushort* __restrict__ B, const float* __restrict__ tw,
        const float* __restrict__ dinv, float* __restrict__ mBvec, int n) {
    __shared__ float sh[4][128];
    int t = threadIdx.x;
    int cp = t & 63;
    int rg = t >> 6;
    int r0 = blockIdx.x * 512;
    int r1 = min(r0 + 512, n);
    float acc0 = 0.f, acc1 = 0.f;
    for (int r = r0 + rg; r < r1; r += 4) {
        float tv = dinv[r] * (tw[r] + dinv[r]);
        uint b = *(const uint*)(B + (size_t)r * 128 + 2 * cp);
        acc0 += bflo(b) * tv;
        acc1 += bfhi(b) * tv;
    }
    sh[rg][2 * cp] = acc0;
    sh[rg][2 * cp + 1] = acc1;
    __syncthreads();
    if (t < 128) {
        float s = sh[0][t] + sh[1][t] + sh[2][t] + sh[3][t];
        atomicAdd(&mBvec[t], s);
    }
}

__global__ void tiny_chain(const float* __restrict__ mBvec, const float* __restrict__ W2,
                           const float* __restrict__ b2, const float* __restrict__ Wd,
                           const float* __restrict__ bd,
                           float* __restrict__ w2s, float* __restrict__ k0, int n) {
    __shared__ float s_sh[128];
    __shared__ float ws_sh[128];
    __shared__ float red[128];
    int t = threadIdx.x;
    float acc = 0.f;
    for (int k = 0; k < 128; ++k) acc += mBvec[k] * W2[k * 128 + t];
    float m = acc / (float)n + b2[t];
    s_sh[t] = 1.f / (1.f + expf(-m));
    __syncthreads();
    acc = 0.f;
    for (int j = 0; j < 128; ++j) acc += Wd[t * 128 + j] * s_sh[j];
    ws_sh[t] = acc;
    __syncthreads();
    acc = 0.f;
    for (int j = 0; j < 128; ++j) acc += W2[t * 128 + j] * ws_sh[j];
    w2s[t] = acc;
    red[t] = b2[t] * ws_sh[t];
    __syncthreads();
    for (int off = 64; off > 0; off >>= 1) {
        if (t < off) red[t] += red[t + off];
        __syncthreads();
    }
    if (t == 0) *k0 = red[0] + bd[0];
}

__global__ __launch_bounds__(256) void sprop(
        const float2* __restrict__ cpair,
        const int* __restrict__ rp, const int* __restrict__ adj,
        const float* __restrict__ dinv, const float* __restrict__ k0,
        float* __restrict__ out, int n) {
    int wave = (blockIdx.x * blockDim.x + threadIdx.x) >> 6;
    int lane = threadIdx.x & 63;
    int q = lane >> 4, l = lane & 15;
    int v = wave * 4 + q;
    if (v >= n) return;
    float a0 = 0.f, a1 = 0.f;
    int beg = rp[v], end = rp[v + 1];
    for (int i = beg + l; i < end; i += 16) {
        float2 c = cpair[adj[i]];
        a0 += c.x;
        a1 += c.y;
    }
#pragma unroll
    for (int off = 1; off < 16; off <<= 1) {
        a0 += __shfl_xor(a0, off);
        a1 += __shfl_xor(a1, off);
    }
    if (l == 0) {
        float dv = dinv[v];
        float kk = *k0;
        float2 cs = cpair[v];
        out[v] = dv * (a0 + cs.x) + kk;
        out[n + v] = dv * (a1 + cs.y) + kk;
    }
}

// ================= launch =================

extern "C" void kernel_launch(void* const* d_in, const int* in_sizes, int n_in,
                              void* d_out, int out_size, void* d_ws, size_t ws_size,
                              hipStream_t stream) {
    const float* x  = (const float*)d_in[0];
    const int*   ei = (const int*)d_in[1];
    const int* perm = (const int*)d_in[2];
    const float* W1 = (const float*)d_in[3];
    const float* b1 = (const float*)d_in[4];
    const float* W2 = (const float*)d_in[5];
    const float* b2 = (const float*)d_in[6];
    const float* Wd = (const float*)d_in[7];
    const float* bd = (const float*)d_in[8];

    const int N = in_sizes[2];
    const int E = in_sizes[1] / 2;
    const int IN = in_sizes[0] / N;  // 512
    const int* src = ei;
    const int* dst = ei + E;
    float* out = (float*)d_out;

    const int NB = (N + 255) >> 8;
    const int M_CNT = NB * CS_G;
    const int chunk = (E + CS_G - 1) / CS_G;

    char* p = (char*)d_ws;
    auto alloc = [&](size_t bytes) -> void* {
        void* r = (void*)p;
        p += (bytes + 511) & ~(size_t)511;
        return r;
    };
    // zero-init group
    float* tw     = (float*)alloc((size_t)N * 4);
    float* mBvec  = (float*)alloc(512);
    size_t zspan = (size_t)((char*)p - (char*)tw);
    // rest
    uint*  counts = (uint*)alloc((size_t)M_CNT * 4);
    uint*  scn    = (uint*)alloc((size_t)(M_CNT + 1) * 4);
    uint*  rec    = (uint*)alloc((size_t)E * 4);
    int*   rp     = (int*)alloc((size_t)(N + 1) * 4);
    int*   adj    = (int*)alloc((size_t)E * 4);
    float* dinv   = (float*)alloc((size_t)N * 4);
    int*   bsum   = (int*)alloc(4096);
    int*   total  = (int*)alloc(64);
    float* w2sv   = (float*)alloc(512);
    float* k0v    = (float*)alloc(64);
    float2* cpair = (float2*)alloc((size_t)N * 8);
    ushort* W1p   = (ushort*)alloc((size_t)512 * 128 * 2);
    ushort* A  = (ushort*)alloc((size_t)N * 128 * 2);
    ushort* B  = (ushort*)alloc((size_t)N * 128 * 2);

    hipMemsetAsync(tw, 0, zspan, stream);

    // --- CSR build (counting sort) ---
    part_hist<<<CS_G, 256, 0, stream>>>(dst, counts, E, NB, chunk);
    int nb_sc = (M_CNT + SC_C - 1) / SC_C;
    scan_part<<<nb_sc, SC_T, 0, stream>>>((const int*)counts, bsum, M_CNT);
    scan_block<<<1, 256, 0, stream>>>(bsum, nb_sc, total);
    scan_write<<<nb_sc, SC_T, 0, stream>>>((const int*)counts, bsum, total, (int*)scn, M_CNT);
    part_scatter<<<CS_G, 256, 0, stream>>>(src, dst, scn, rec, E, NB, chunk);
    bucket_build<<<NB, 256, 0, stream>>>(scn, rec, rp, adj, dinv, tw, E, NB, N);

    // --- dense pipeline ---
    pack_w<<<(IN / 32) * 8, 64, 0, stream>>>(W1, W1p);

    int gemm_blocks = (N + 63) / 64;
    int p4_blocks = ((N + 3) / 4 + 3) / 4;

    gemm1_mfma<<<gemm_blocks, 256, 0, stream>>>(x, W1p, A, N, IN);
    prop_b0<<<p4_blocks, 256, 0, stream>>>(A, rp, adj, dinv, b1, B, N);
    wcolsum<<<(N + 511) / 512, 256, 0, stream>>>(B, tw, dinv, mBvec, N);
    tiny_chain<<<1, 128, 0, stream>>>(mBvec, W2, b2, Wd, bd, w2sv, k0v, N);
    prop_b1<<<p4_blocks, 256, 0, stream>>>(A, B, rp, adj, dinv, perm, b1, w2sv, cpair, N);
    sprop<<<p4_blocks, 256, 0, stream>>>(cpair, rp, adj, dinv, k0v, out, N);
}

// Round 7
// 505.422 us; speedup vs baseline: 4.5333x; 1.2681x over previous
//
#include <hip/hip_runtime.h>
#include <hip/hip_bf16.h>

typedef unsigned int uint;
typedef unsigned short ushort;
typedef __attribute__((ext_vector_type(8))) short bf16x8;
typedef __attribute__((ext_vector_type(4))) float f32x4;

static __device__ __forceinline__ ushort f2bf(float f) {
    uint u = __builtin_bit_cast(uint, f);
    return (ushort)((u + 0x7FFFu + ((u >> 16) & 1u)) >> 16);
}
static __device__ __forceinline__ uint pk2(float lo, float hi) {
    return (uint)f2bf(lo) | ((uint)f2bf(hi) << 16);
}
static __device__ __forceinline__ float bflo(uint u) { return __builtin_bit_cast(float, u << 16); }
static __device__ __forceinline__ float bfhi(uint u) { return __builtin_bit_cast(float, u & 0xFFFF0000u); }

// ================= CSR build: fused dual counting sort =================
// dst-sort -> adj (in-neighbors); src-sort -> records for tw reduction.
// bucket = node >> 8 (256 nodes per bucket). NB <= 512. Node ids < 2^24.

#define CS_G 512   // partition grid

__global__ __launch_bounds__(256) void part_hist_dual(
        const int* __restrict__ src, const int* __restrict__ dst,
        uint* __restrict__ counts, int E, int NB, int chunk) {
    __shared__ uint h0[512], h1[512];
    int t = threadIdx.x;
    for (int b = t; b < 512; b += 256) { h0[b] = 0; h1[b] = 0; }
    __syncthreads();
    int s0 = blockIdx.x * chunk;
    int s1 = min(s0 + chunk, E);
    int i = s0 + t * 4;
    for (; i + 4 <= s1; i += 1024) {
        int4 d4 = *(const int4*)(dst + i);
        int4 s4 = *(const int4*)(src + i);
        atomicAdd(&h0[d4.x >> 8], 1u); atomicAdd(&h0[d4.y >> 8], 1u);
        atomicAdd(&h0[d4.z >> 8], 1u); atomicAdd(&h0[d4.w >> 8], 1u);
        atomicAdd(&h1[s4.x >> 8], 1u); atomicAdd(&h1[s4.y >> 8], 1u);
        atomicAdd(&h1[s4.z >> 8], 1u); atomicAdd(&h1[s4.w >> 8], 1u);
    }
    for (int k = i; k < min(i + 4, s1); ++k) {
        atomicAdd(&h0[dst[k] >> 8], 1u);
        atomicAdd(&h1[src[k] >> 8], 1u);
    }
    __syncthreads();
    for (int b = t; b < NB; b += 256) {
        counts[(size_t)b * CS_G + blockIdx.x] = h0[b];
        counts[(size_t)(NB + b) * CS_G + blockIdx.x] = h1[b];
    }
}

__global__ __launch_bounds__(256) void part_scatter_dual(
        const int* __restrict__ src, const int* __restrict__ dst,
        const uint* __restrict__ scn, uint* __restrict__ rec,
        int E, int NB, int chunk) {
    __shared__ uint cur0[512], cur1[512];
    int t = threadIdx.x;
    for (int b = t; b < NB; b += 256) {
        cur0[b] = scn[(size_t)b * CS_G + blockIdx.x];
        cur1[b] = scn[(size_t)(NB + b) * CS_G + blockIdx.x];
    }
    __syncthreads();
    int s0 = blockIdx.x * chunk;
    int s1 = min(s0 + chunk, E);
    int i = s0 + t * 4;
    for (; i + 4 <= s1; i += 1024) {
        int4 d4 = *(const int4*)(dst + i);
        int4 s4 = *(const int4*)(src + i);
        int dd[4] = {d4.x, d4.y, d4.z, d4.w};
        int ss[4] = {s4.x, s4.y, s4.z, s4.w};
#pragma unroll
        for (int k = 0; k < 4; ++k) {
            uint slotD = atomicAdd(&cur0[dd[k] >> 8], 1u);
            rec[slotD] = ((uint)(dd[k] & 255) << 24) | (uint)ss[k];
            uint slotS = atomicAdd(&cur1[ss[k] >> 8], 1u);
            rec[slotS] = ((uint)(ss[k] & 255) << 24) | (uint)dd[k];
        }
    }
    for (int k = i; k < min(i + 4, s1); ++k) {
        int d = dst[k], s = src[k];
        uint slotD = atomicAdd(&cur0[d >> 8], 1u);
        rec[slotD] = ((uint)(d & 255) << 24) | (uint)s;
        uint slotS = atomicAdd(&cur1[s >> 8], 1u);
        rec[slotS] = ((uint)(s & 255) << 24) | (uint)d;
    }
}

// per dst-bucket: per-node counts -> rp, dinv; scatter adj (no tw here)
__global__ __launch_bounds__(256) void bucket_build(
        const uint* __restrict__ scn, const uint* __restrict__ rec,
        int* __restrict__ rp, int* __restrict__ adj,
        float* __restrict__ dinv, int NB, int n) {
    __shared__ uint cnt[256];
    __shared__ uint sc[2][256];
    int b = blockIdx.x, t = threadIdx.x;
    uint base = scn[(size_t)b * CS_G];
    uint bend = scn[(size_t)(b + 1) * CS_G];   // valid: b+1<=NB -> start of src section == E
    cnt[t] = 0;
    __syncthreads();
    for (uint i = base + t; i < bend; i += 256)
        atomicAdd(&cnt[rec[i] >> 24], 1u);
    __syncthreads();
    uint vcnt = cnt[t];
    float dv = rsqrtf((float)(vcnt + 1));
    sc[0][t] = vcnt;
    __syncthreads();
    int pb = 0;
    for (int off = 1; off < 256; off <<= 1) {
        uint add = (t >= off) ? sc[pb][t - off] : 0u;
        sc[pb ^ 1][t] = sc[pb][t] + add;
        pb ^= 1;
        __syncthreads();
    }
    uint excl = sc[pb][t] - vcnt;
    uint off0 = base + excl;
    int vtx = b * 256 + t;
    if (vtx < n) {
        rp[vtx] = (int)off0;
        dinv[vtx] = dv;
    }
    if (b == 0 && t == 0) rp[n] = (int)scn[(size_t)NB * CS_G];  // = E
    cnt[t] = off0;   // repurpose as cursor
    __syncthreads();
    for (uint i = base + t; i < bend; i += 256) {
        uint r = rec[i];
        uint slot = atomicAdd(&cnt[r >> 24], 1u);
        adj[slot] = (int)(r & 0xFFFFFFu);
    }
}

// per src-bucket: tw via LDS atomics, then fused weighted col-sum of B
__global__ __launch_bounds__(256) void bucket_tw_colsum(
        const uint* __restrict__ scn, const uint* __restrict__ rec,
        const float* __restrict__ dinv, const ushort* __restrict__ B,
        float* __restrict__ mBvec, int NB, int n) {
    __shared__ float tw_sh[256];
    __shared__ float tv_sh[256];
    __shared__ float sh[4][128];
    int b = blockIdx.x, t = threadIdx.x;
    uint base = scn[(size_t)(NB + b) * CS_G];
    uint bend = scn[(size_t)(NB + b + 1) * CS_G];  // last = scn[2*NB*CS_G] = 2E
    tw_sh[t] = 0.f;
    __syncthreads();
    for (uint i = base + t; i < bend; i += 256) {
        uint r = rec[i];
        atomicAdd(&tw_sh[r >> 24], dinv[r & 0xFFFFFFu]);
    }
    __syncthreads();
    int vtx = b * 256 + t;
    float dv = (vtx < n) ? dinv[vtx] : 0.f;
    tv_sh[t] = dv * (tw_sh[t] + dv);
    __syncthreads();
    int cp = t & 63, rg = t >> 6;
    int rmax = min(256, n - b * 256);
    float acc0 = 0.f, acc1 = 0.f;
    for (int r = rg; r < rmax; r += 4) {
        float tv = tv_sh[r];
        uint bb = *(const uint*)(B + ((size_t)(b * 256 + r)) * 128 + 2 * cp);
        acc0 += bflo(bb) * tv;
        acc1 += bfhi(bb) * tv;
    }
    sh[rg][2 * cp] = acc0;
    sh[rg][2 * cp + 1] = acc1;
    __syncthreads();
    if (t < 128)
        atomicAdd(&mBvec[t], sh[0][t] + sh[1][t] + sh[2][t] + sh[3][t]);
}

// ================= scan machinery =================

#define SC_T 256
#define SC_C 1024

__global__ void scan_part(const int* __restrict__ deg, int* __restrict__ bsum, int n) {
    __shared__ int sh[SC_T];
    int t = threadIdx.x;
    int base = blockIdx.x * SC_C;
    int s = 0;
    for (int i = 0; i < 4; i++) {
        int idx = base + t * 4 + i;
        if (idx < n) s += deg[idx];
    }
    sh[t] = s;
    __syncthreads();
    for (int off = 128; off > 0; off >>= 1) {
        if (t < off) sh[t] += sh[t + off];
        __syncthreads();
    }
    if (t == 0) bsum[blockIdx.x] = sh[0];
}

// parallel exclusive scan of nb (<=1024) block sums, one block of 256
__global__ void scan_block(int* bsum, int nb, int* total) {
    __shared__ int sh[256];
    int t = threadIdx.x;
    int v[4];
    int s = 0;
#pragma unroll
    for (int i = 0; i < 4; i++) {
        int idx = t * 4 + i;
        v[i] = (idx < nb) ? bsum[idx] : 0;
        s += v[i];
    }
    sh[t] = s;
    __syncthreads();
    for (int off = 1; off < 256; off <<= 1) {
        int u = (t >= off) ? sh[t - off] : 0;
        __syncthreads();
        sh[t] += u;
        __syncthreads();
    }
    int excl = sh[t] - s;
#pragma unroll
    for (int i = 0; i < 4; i++) {
        int idx = t * 4 + i;
        if (idx < nb) { bsum[idx] = excl; excl += v[i]; }
    }
    if (t == 255) *total = sh[255];
}

__global__ void scan_write(const int* __restrict__ deg, const int* __restrict__ bsum,
                           const int* __restrict__ total, int* __restrict__ rp, int n) {
    __shared__ int sh[SC_T];
    int t = threadIdx.x;
    int base = blockIdx.x * SC_C;
    int vals[4];
    int s = 0;
    for (int i = 0; i < 4; i++) {
        int idx = base + t * 4 + i;
        vals[i] = (idx < n) ? deg[idx] : 0;
        s += vals[i];
    }
    sh[t] = s;
    __syncthreads();
    for (int off = 1; off < SC_T; off <<= 1) {
        int v = (t >= off) ? sh[t - off] : 0;
        __syncthreads();
        sh[t] += v;
        __syncthreads();
    }
    int excl = sh[t] - s + bsum[blockIdx.x];
    for (int i = 0; i < 4; i++) {
        int idx = base + t * 4 + i;
        if (idx < n) { rp[idx] = excl; excl += vals[i]; }
    }
    if (blockIdx.x == 0 && t == 0) rp[n] = *total;
}

// ================= W1 pre-pack into MFMA B-fragment layout =================

__global__ void pack_w(const float* __restrict__ W, ushort* __restrict__ Wp) {
    int kc = blockIdx.x >> 3, n = blockIdx.x & 7;
    int l = threadIdx.x;
    ushort o[8];
#pragma unroll
    for (int j = 0; j < 8; ++j) {
        float v = W[(size_t)(kc * 32 + ((l >> 4) * 8) + j) * 128 + n * 16 + (l & 15)];
        o[j] = f2bf(v);
    }
    uint4 pk;
    pk.x = (uint)o[0] | ((uint)o[1] << 16);
    pk.y = (uint)o[2] | ((uint)o[3] << 16);
    pk.z = (uint)o[4] | ((uint)o[5] << 16);
    pk.w = (uint)o[6] | ((uint)o[7] << 16);
    *(uint4*)(Wp + ((size_t)(kc * 8 + n) * 64 + l) * 8) = pk;
}

// ================= GEMM1: Cb[M,128](bf16) = X[M,K](fp32) @ W1 (packed) =================

__global__ __launch_bounds__(256) void gemm1_mfma(
        const float* __restrict__ X, const ushort* __restrict__ Wp,
        ushort* __restrict__ Cb, int M, int K) {
    __shared__ ushort As[2][64][40];
    int t = threadIdx.x, lane = t & 63, w = t >> 6;
    int brow = blockIdx.x * 64;
    int KC = K >> 5;
    f32x4 acc[8] = {};
    int sr = t >> 2, sk = (t & 3) * 8;
    int gr = brow + sr;
    bool xok = gr < M;
    int frow = w * 16 + (lane & 15);
    int fk = (lane >> 4) * 8;

    auto loadpk = [&](int kc) -> uint4 {
        float4 xa = make_float4(0.f, 0.f, 0.f, 0.f), xb = xa;
        if (xok) {
            const float* xp = X + (size_t)gr * K + kc * 32 + sk;
            xa = *(const float4*)xp;
            xb = *(const float4*)(xp + 4);
        }
        uint4 pk;
        pk.x = pk2(xa.x, xa.y);
        pk.y = pk2(xa.z, xa.w);
        pk.z = pk2(xb.x, xb.y);
        pk.w = pk2(xb.z, xb.w);
        return pk;
    };

    uint4 cur = loadpk(0);
    int buf = 0;
    for (int kc = 0; kc < KC; ++kc) {
        *(uint4*)&As[buf][sr][sk] = cur;
        __syncthreads();
        if (kc + 1 < KC) cur = loadpk(kc + 1);
        bf16x8 af = *(const bf16x8*)&As[buf][frow][fk];
        const ushort* wbase = Wp + ((size_t)(kc * 8) * 64 + lane) * 8;
#pragma unroll
        for (int n = 0; n < 8; ++n) {
            bf16x8 bfr = *(const bf16x8*)(wbase + (size_t)n * 64 * 8);
            acc[n] = __builtin_amdgcn_mfma_f32_16x16x32_bf16(af, bfr, acc[n], 0, 0, 0);
        }
        buf ^= 1;
    }
    int colbase = lane & 15;
    int rowbase = brow + w * 16 + ((lane >> 4) << 2);
#pragma unroll
    for (int n = 0; n < 8; ++n) {
#pragma unroll
        for (int r = 0; r < 4; ++r) {
            int grr = rowbase + r;
            if (grr < M) Cb[(size_t)grr * 128 + n * 16 + colbase] = f2bf(acc[n][r]);
        }
    }
}

// ================= layer-1 propagation, branch 0: B = relu(S*A + b1) =================

#define ACC8(acc, g, w)                                   \
    acc[0] += bflo(g.x) * w; acc[1] += bfhi(g.x) * w;     \
    acc[2] += bflo(g.y) * w; acc[3] += bfhi(g.y) * w;     \
    acc[4] += bflo(g.z) * w; acc[5] += bfhi(g.z) * w;     \
    acc[6] += bflo(g.w) * w; acc[7] += bfhi(g.w) * w;

__global__ __launch_bounds__(256) void prop_b0(
        const ushort* __restrict__ A,
        const int* __restrict__ rp, const int* __restrict__ adj,
        const float* __restrict__ dinv, const float* __restrict__ bias,
        ushort* __restrict__ B, int n) {
    int wave = (blockIdx.x * blockDim.x + threadIdx.x) >> 6;
    int lane = threadIdx.x & 63;
    int q = lane >> 4, l = lane & 15;
    int v = wave * 4 + q;
    bool vok = v < n;
    int vc = vok ? v : (n - 1);
    float dv = dinv[vc];

    uint4 r0 = *(const uint4*)(A + (size_t)vc * 128 + 8 * l);
    float a0[8];
    a0[0] = bflo(r0.x) * dv; a0[1] = bfhi(r0.x) * dv;
    a0[2] = bflo(r0.y) * dv; a0[3] = bfhi(r0.y) * dv;
    a0[4] = bflo(r0.z) * dv; a0[5] = bfhi(r0.z) * dv;
    a0[6] = bflo(r0.w) * dv; a0[7] = bfhi(r0.w) * dv;

    int i = rp[vc], end = rp[vc + 1];
    int un[4];
#pragma unroll
    for (int k = 0; k < 4; ++k) un[k] = (i + k < end) ? adj[i + k] : vc;

    while (__ballot(i < end)) {
        int uc[4];
#pragma unroll
        for (int k = 0; k < 4; ++k) uc[k] = un[k];
        uint4 g0[4];
#pragma unroll
        for (int k = 0; k < 4; ++k) g0[k] = *(const uint4*)(A + (size_t)uc[k] * 128 + 8 * l);
        float du[4];
#pragma unroll
        for (int k = 0; k < 4; ++k) du[k] = (i + k < end) ? dinv[uc[k]] : 0.f;
        i += 4;
#pragma unroll
        for (int k = 0; k < 4; ++k) un[k] = (i + k < end) ? adj[i + k] : vc;
#pragma unroll
        for (int k = 0; k < 4; ++k) {
            float w = du[k];
            ACC8(a0, g0[k], w)
        }
    }
    if (!vok) return;
    float4 bA = *(const float4*)(bias + 8 * l);
    float4 bB = *(const float4*)(bias + 8 * l + 4);
    float bb[8] = {bA.x, bA.y, bA.z, bA.w, bB.x, bB.y, bB.z, bB.w};
#pragma unroll
    for (int j = 0; j < 8; ++j)
        a0[j] = fmaxf(a0[j] * dv + bb[j], 0.f);
    uint4 o;
    o.x = pk2(a0[0], a0[1]); o.y = pk2(a0[2], a0[3]);
    o.z = pk2(a0[4], a0[5]); o.w = pk2(a0[6], a0[7]);
    *(uint4*)(B + (size_t)v * 128 + 8 * l) = o;
}

// ================= branch 1 + fused dots =================

__global__ __launch_bounds__(256) void prop_b1(
        const ushort* __restrict__ A, const ushort* __restrict__ B,
        const int* __restrict__ rp, const int* __restrict__ adj,
        const float* __restrict__ dinv, const int* __restrict__ perm,
        const float* __restrict__ bias, const float* __restrict__ w2s,
        float2* __restrict__ cpair, int n) {
    int wave = (blockIdx.x * blockDim.x + threadIdx.x) >> 6;
    int lane = threadIdx.x & 63;
    int q = lane >> 4, l = lane & 15;
    int v = wave * 4 + q;
    bool vok = v < n;
    int vc = vok ? v : (n - 1);
    float dv = dinv[vc];
    int self = perm[vc];

    uint4 r1 = *(const uint4*)(A + (size_t)self * 128 + 8 * l);
    float a1[8];
    a1[0] = bflo(r1.x) * dv; a1[1] = bfhi(r1.x) * dv;
    a1[2] = bflo(r1.y) * dv; a1[3] = bfhi(r1.y) * dv;
    a1[4] = bflo(r1.z) * dv; a1[5] = bfhi(r1.z) * dv;
    a1[6] = bflo(r1.w) * dv; a1[7] = bfhi(r1.w) * dv;

    int i = rp[vc], end = rp[vc + 1];
    int un[4];
#pragma unroll
    for (int k = 0; k < 4; ++k) un[k] = (i + k < end) ? adj[i + k] : vc;

    while (__ballot(i < end)) {
        int uc[4];
#pragma unroll
        for (int k = 0; k < 4; ++k) uc[k] = un[k];
        int uu[4];
#pragma unroll
        for (int k = 0; k < 4; ++k) uu[k] = perm[uc[k]];
        uint4 g1[4];
#pragma unroll
        for (int k = 0; k < 4; ++k) g1[k] = *(const uint4*)(A + (size_t)uu[k] * 128 + 8 * l);
        float du[4];
#pragma unroll
        for (int k = 0; k < 4; ++k) du[k] = (i + k < end) ? dinv[uc[k]] : 0.f;
        i += 4;
#pragma unroll
        for (int k = 0; k < 4; ++k) un[k] = (i + k < end) ? adj[i + k] : vc;
#pragma unroll
        for (int k = 0; k < 4; ++k) {
            float w = du[k];
            ACC8(a1, g1[k], w)
        }
    }
    if (!vok) return;
    float4 bA = *(const float4*)(bias + 8 * l);
    float4 bB = *(const float4*)(bias + 8 * l + 4);
    float bb[8] = {bA.x, bA.y, bA.z, bA.w, bB.x, bB.y, bB.z, bB.w};
    float4 wA = *(const float4*)(w2s + 8 * l);
    float4 wB = *(const float4*)(w2s + 8 * l + 4);
    float ww[8] = {wA.x, wA.y, wA.z, wA.w, wB.x, wB.y, wB.z, wB.w};
    float c1 = 0.f;
#pragma unroll
    for (int j = 0; j < 8; ++j)
        c1 += fmaxf(a1[j] * dv + bb[j], 0.f) * ww[j];
    uint4 b0 = *(const uint4*)(B + (size_t)vc * 128 + 8 * l);
    float c0 = bflo(b0.x) * ww[0] + bfhi(b0.x) * ww[1]
             + bflo(b0.y) * ww[2] + bfhi(b0.y) * ww[3]
             + bflo(b0.z) * ww[4] + bfhi(b0.z) * ww[5]
             + bflo(b0.w) * ww[6] + bfhi(b0.w) * ww[7];
#pragma unroll
    for (int off = 1; off < 16; off <<= 1) {
        c0 += __shfl_xor(c0, off);
        c1 += __shfl_xor(c1, off);
    }
    if (l == 0) cpair[v] = make_float2(dv * c0, dv * c1);
}

// ================= readout =================

__global__ void tiny_chain(const float* __restrict__ mBvec, const float* __restrict__ W2,
                           const float* __restrict__ b2, const float* __restrict__ Wd,
                           const float* __restrict__ bd,
                           float* __restrict__ w2s, float* __restrict__ k0, int n) {
    __shared__ float s_sh[128];
    __shared__ float ws_sh[128];
    __shared__ float red[128];
    int t = threadIdx.x;
    float acc = 0.f;
    for (int k = 0; k < 128; ++k) acc += mBvec[k] * W2[k * 128 + t];
    float m = acc / (float)n + b2[t];
    s_sh[t] = 1.f / (1.f + expf(-m));
    __syncthreads();
    acc = 0.f;
    for (int j = 0; j < 128; ++j) acc += Wd[t * 128 + j] * s_sh[j];
    ws_sh[t] = acc;
    __syncthreads();
    acc = 0.f;
    for (int j = 0; j < 128; ++j) acc += W2[t * 128 + j] * ws_sh[j];
    w2s[t] = acc;
    red[t] = b2[t] * ws_sh[t];
    __syncthreads();
    for (int off = 64; off > 0; off >>= 1) {
        if (t < off) red[t] += red[t + off];
        __syncthreads();
    }
    if (t == 0) *k0 = red[0] + bd[0];
}

__global__ __launch_bounds__(256) void sprop(
        const float2* __restrict__ cpair,
        const int* __restrict__ rp, const int* __restrict__ adj,
        const float* __restrict__ dinv, const float* __restrict__ k0,
        float* __restrict__ out, int n) {
    int wave = (blockIdx.x * blockDim.x + threadIdx.x) >> 6;
    int lane = threadIdx.x & 63;
    int q = lane >> 4, l = lane & 15;
    int v = wave * 4 + q;
    if (v >= n) return;
    float a0 = 0.f, a1 = 0.f;
    int beg = rp[v], end = rp[v + 1];
    for (int i = beg + l; i < end; i += 16) {
        float2 c = cpair[adj[i]];
        a0 += c.x;
        a1 += c.y;
    }
#pragma unroll
    for (int off = 1; off < 16; off <<= 1) {
        a0 += __shfl_xor(a0, off);
        a1 += __shfl_xor(a1, off);
    }
    if (l == 0) {
        float dv = dinv[v];
        float kk = *k0;
        float2 cs = cpair[v];
        out[v] = dv * (a0 + cs.x) + kk;
        out[n + v] = dv * (a1 + cs.y) + kk;
    }
}

// ================= launch =================

extern "C" void kernel_launch(void* const* d_in, const int* in_sizes, int n_in,
                              void* d_out, int out_size, void* d_ws, size_t ws_size,
                              hipStream_t stream) {
    const float* x  = (const float*)d_in[0];
    const int*   ei = (const int*)d_in[1];
    const int* perm = (const int*)d_in[2];
    const float* W1 = (const float*)d_in[3];
    const float* b1 = (const float*)d_in[4];
    const float* W2 = (const float*)d_in[5];
    const float* b2 = (const float*)d_in[6];
    const float* Wd = (const float*)d_in[7];
    const float* bd = (const float*)d_in[8];

    const int N = in_sizes[2];
    const int E = in_sizes[1] / 2;
    const int IN = in_sizes[0] / N;  // 512
    const int* src = ei;
    const int* dst = ei + E;
    float* out = (float*)d_out;

    const int NB = (N + 255) >> 8;          // <= 512
    const int M2 = 2 * NB * CS_G;           // dual counts array size
    int chunk = (E + CS_G - 1) / CS_G;
    chunk = (chunk + 3) & ~3;               // multiple of 4 for int4 loads

    char* p = (char*)d_ws;
    auto alloc = [&](size_t bytes) -> void* {
        void* r = (void*)p;
        p += (bytes + 511) & ~(size_t)511;
        return r;
    };
    float* mBvec  = (float*)alloc(512);     // zeroed each call
    uint*  counts = (uint*)alloc((size_t)M2 * 4);
    uint*  scn    = (uint*)alloc((size_t)(M2 + 1) * 4);
    uint*  rec    = (uint*)alloc((size_t)2 * E * 4);
    int*   rp     = (int*)alloc((size_t)(N + 1) * 4);
    int*   adj    = (int*)alloc((size_t)E * 4);
    float* dinv   = (float*)alloc((size_t)N * 4);
    int*   bsum   = (int*)alloc(4096);
    int*   total  = (int*)alloc(64);
    float* w2sv   = (float*)alloc(512);
    float* k0v    = (float*)alloc(64);
    float2* cpair = (float2*)alloc((size_t)N * 8);
    ushort* W1p   = (ushort*)alloc((size_t)512 * 128 * 2);
    ushort* A  = (ushort*)alloc((size_t)N * 128 * 2);
    ushort* B  = (ushort*)alloc((size_t)N * 128 * 2);

    hipMemsetAsync(mBvec, 0, 512, stream);

    // --- fused dual counting sort ---
    part_hist_dual<<<CS_G, 256, 0, stream>>>(src, dst, counts, E, NB, chunk);
    int nb_sc = (M2 + SC_C - 1) / SC_C;     // <= 1024
    scan_part<<<nb_sc, SC_T, 0, stream>>>((const int*)counts, bsum, M2);
    scan_block<<<1, 256, 0, stream>>>(bsum, nb_sc, total);
    scan_write<<<nb_sc, SC_T, 0, stream>>>((const int*)counts, bsum, total, (int*)scn, M2);
    part_scatter_dual<<<CS_G, 256, 0, stream>>>(src, dst, scn, rec, E, NB, chunk);
    bucket_build<<<NB, 256, 0, stream>>>(scn, rec, rp, adj, dinv, NB, N);

    // --- dense pipeline ---
    pack_w<<<(IN / 32) * 8, 64, 0, stream>>>(W1, W1p);

    int gemm_blocks = (N + 63) / 64;
    int p4_blocks = ((N + 3) / 4 + 3) / 4;

    gemm1_mfma<<<gemm_blocks, 256, 0, stream>>>(x, W1p, A, N, IN);
    prop_b0<<<p4_blocks, 256, 0, stream>>>(A, rp, adj, dinv, b1, B, N);
    bucket_tw_colsum<<<NB, 256, 0, stream>>>(scn, rec, dinv, B, mBvec, NB, N);
    tiny_chain<<<1, 128, 0, stream>>>(mBvec, W2, b2, Wd, bd, w2sv, k0v, N);
    prop_b1<<<p4_blocks, 256, 0, stream>>>(A, B, rp, adj, dinv, perm, b1, w2sv, cpair, N);
    sprop<<<p4_blocks, 256, 0, stream>>>(cpair, rp, adj, dinv, k0v, out, N);
}

// Round 8
// 494.410 us; speedup vs baseline: 4.6343x; 1.0223x over previous
//
#include <hip/hip_runtime.h>
#include <hip/hip_bf16.h>

typedef unsigned int uint;
typedef unsigned short ushort;
typedef __attribute__((ext_vector_type(8))) short bf16x8;
typedef __attribute__((ext_vector_type(4))) float f32x4;

static __device__ __forceinline__ ushort f2bf(float f) {
    uint u = __builtin_bit_cast(uint, f);
    return (ushort)((u + 0x7FFFu + ((u >> 16) & 1u)) >> 16);
}
static __device__ __forceinline__ uint pk2(float lo, float hi) {
    return (uint)f2bf(lo) | ((uint)f2bf(hi) << 16);
}
static __device__ __forceinline__ float bflo(uint u) { return __builtin_bit_cast(float, u << 16); }
static __device__ __forceinline__ float bfhi(uint u) { return __builtin_bit_cast(float, u & 0xFFFF0000u); }

// ================= CSR build: fused dual counting sort =================
// dst-sort -> adj (in-neighbors); src-sort -> records for tw reduction.
// bucket = node >> 8 (256 nodes per bucket). NB <= 512. Node ids < 2^24.

#define CS_G 512   // partition grid

__global__ __launch_bounds__(256) void part_hist_dual(
        const int* __restrict__ src, const int* __restrict__ dst,
        uint* __restrict__ counts, int E, int NB, int chunk) {
    __shared__ uint h0[512], h1[512];
    int t = threadIdx.x;
    for (int b = t; b < 512; b += 256) { h0[b] = 0; h1[b] = 0; }
    __syncthreads();
    int s0 = blockIdx.x * chunk;
    int s1 = min(s0 + chunk, E);
    int i = s0 + t * 4;
    for (; i + 4 <= s1; i += 1024) {
        int4 d4 = *(const int4*)(dst + i);
        int4 s4 = *(const int4*)(src + i);
        atomicAdd(&h0[d4.x >> 8], 1u); atomicAdd(&h0[d4.y >> 8], 1u);
        atomicAdd(&h0[d4.z >> 8], 1u); atomicAdd(&h0[d4.w >> 8], 1u);
        atomicAdd(&h1[s4.x >> 8], 1u); atomicAdd(&h1[s4.y >> 8], 1u);
        atomicAdd(&h1[s4.z >> 8], 1u); atomicAdd(&h1[s4.w >> 8], 1u);
    }
    for (int k = i; k < min(i + 4, s1); ++k) {
        atomicAdd(&h0[dst[k] >> 8], 1u);
        atomicAdd(&h1[src[k] >> 8], 1u);
    }
    __syncthreads();
    for (int b = t; b < NB; b += 256) {
        counts[(size_t)b * CS_G + blockIdx.x] = h0[b];
        counts[(size_t)(NB + b) * CS_G + blockIdx.x] = h1[b];
    }
}

__global__ __launch_bounds__(256) void part_scatter_dual(
        const int* __restrict__ src, const int* __restrict__ dst,
        const uint* __restrict__ scn, uint* __restrict__ rec,
        int E, int NB, int chunk) {
    __shared__ uint cur0[512], cur1[512];
    int t = threadIdx.x;
    for (int b = t; b < NB; b += 256) {
        cur0[b] = scn[(size_t)b * CS_G + blockIdx.x];
        cur1[b] = scn[(size_t)(NB + b) * CS_G + blockIdx.x];
    }
    __syncthreads();
    int s0 = blockIdx.x * chunk;
    int s1 = min(s0 + chunk, E);
    int i = s0 + t * 4;
    for (; i + 4 <= s1; i += 1024) {
        int4 d4 = *(const int4*)(dst + i);
        int4 s4 = *(const int4*)(src + i);
        int dd[4] = {d4.x, d4.y, d4.z, d4.w};
        int ss[4] = {s4.x, s4.y, s4.z, s4.w};
#pragma unroll
        for (int k = 0; k < 4; ++k) {
            uint slotD = atomicAdd(&cur0[dd[k] >> 8], 1u);
            rec[slotD] = ((uint)(dd[k] & 255) << 24) | (uint)ss[k];
            uint slotS = atomicAdd(&cur1[ss[k] >> 8], 1u);
            rec[slotS] = ((uint)(ss[k] & 255) << 24) | (uint)dd[k];
        }
    }
    for (int k = i; k < min(i + 4, s1); ++k) {
        int d = dst[k], s = src[k];
        uint slotD = atomicAdd(&cur0[d >> 8], 1u);
        rec[slotD] = ((uint)(d & 255) << 24) | (uint)s;
        uint slotS = atomicAdd(&cur1[s >> 8], 1u);
        rec[slotS] = ((uint)(s & 255) << 24) | (uint)d;
    }
}

// per dst-bucket: per-node counts -> rp, dinv; scatter adj
__global__ __launch_bounds__(256) void bucket_build(
        const uint* __restrict__ scn, const uint* __restrict__ rec,
        int* __restrict__ rp, int* __restrict__ adj,
        float* __restrict__ dinv, int NB, int n) {
    __shared__ uint cnt[256];
    __shared__ uint sc[2][256];
    int b = blockIdx.x, t = threadIdx.x;
    uint base = scn[(size_t)b * CS_G];
    uint bend = scn[(size_t)(b + 1) * CS_G];
    cnt[t] = 0;
    __syncthreads();
    for (uint i = base + t; i < bend; i += 256)
        atomicAdd(&cnt[rec[i] >> 24], 1u);
    __syncthreads();
    uint vcnt = cnt[t];
    float dv = rsqrtf((float)(vcnt + 1));
    sc[0][t] = vcnt;
    __syncthreads();
    int pb = 0;
    for (int off = 1; off < 256; off <<= 1) {
        uint add = (t >= off) ? sc[pb][t - off] : 0u;
        sc[pb ^ 1][t] = sc[pb][t] + add;
        pb ^= 1;
        __syncthreads();
    }
    uint excl = sc[pb][t] - vcnt;
    uint off0 = base + excl;
    int vtx = b * 256 + t;
    if (vtx < n) {
        rp[vtx] = (int)off0;
        dinv[vtx] = dv;
    }
    if (b == 0 && t == 0) rp[n] = (int)scn[(size_t)NB * CS_G];  // = E
    cnt[t] = off0;   // repurpose as cursor
    __syncthreads();
    for (uint i = base + t; i < bend; i += 256) {
        uint r = rec[i];
        uint slot = atomicAdd(&cnt[r >> 24], 1u);
        adj[slot] = (int)(r & 0xFFFFFFu);
    }
}

// per src-bucket: tw via LDS atomics -> tv[v] = dv*(tw[v]+dv)
__global__ __launch_bounds__(256) void bucket_tw(
        const uint* __restrict__ scn, const uint* __restrict__ rec,
        const float* __restrict__ dinv, float* __restrict__ tv,
        int NB, int n) {
    __shared__ float tw_sh[256];
    int b = blockIdx.x, t = threadIdx.x;
    uint base = scn[(size_t)(NB + b) * CS_G];
    uint bend = scn[(size_t)(NB + b + 1) * CS_G];   // last = scn[2*NB*CS_G] = 2E
    tw_sh[t] = 0.f;
    __syncthreads();
    for (uint i = base + t; i < bend; i += 256) {
        uint r = rec[i];
        atomicAdd(&tw_sh[r >> 24], dinv[r & 0xFFFFFFu]);
    }
    __syncthreads();
    int vtx = b * 256 + t;
    if (vtx < n) {
        float dv = dinv[vtx];
        tv[vtx] = dv * (tw_sh[t] + dv);
    }
}

// ================= scan machinery =================

#define SC_T 256
#define SC_C 1024

__global__ void scan_part(const int* __restrict__ deg, int* __restrict__ bsum, int n) {
    __shared__ int sh[SC_T];
    int t = threadIdx.x;
    int base = blockIdx.x * SC_C;
    int s = 0;
    for (int i = 0; i < 4; i++) {
        int idx = base + t * 4 + i;
        if (idx < n) s += deg[idx];
    }
    sh[t] = s;
    __syncthreads();
    for (int off = 128; off > 0; off >>= 1) {
        if (t < off) sh[t] += sh[t + off];
        __syncthreads();
    }
    if (t == 0) bsum[blockIdx.x] = sh[0];
}

__global__ void scan_block(int* bsum, int nb, int* total) {
    __shared__ int sh[256];
    int t = threadIdx.x;
    int v[4];
    int s = 0;
#pragma unroll
    for (int i = 0; i < 4; i++) {
        int idx = t * 4 + i;
        v[i] = (idx < nb) ? bsum[idx] : 0;
        s += v[i];
    }
    sh[t] = s;
    __syncthreads();
    for (int off = 1; off < 256; off <<= 1) {
        int u = (t >= off) ? sh[t - off] : 0;
        __syncthreads();
        sh[t] += u;
        __syncthreads();
    }
    int excl = sh[t] - s;
#pragma unroll
    for (int i = 0; i < 4; i++) {
        int idx = t * 4 + i;
        if (idx < nb) { bsum[idx] = excl; excl += v[i]; }
    }
    if (t == 255) *total = sh[255];
}

__global__ void scan_write(const int* __restrict__ deg, const int* __restrict__ bsum,
                           const int* __restrict__ total, int* __restrict__ rp, int n) {
    __shared__ int sh[SC_T];
    int t = threadIdx.x;
    int base = blockIdx.x * SC_C;
    int vals[4];
    int s = 0;
    for (int i = 0; i < 4; i++) {
        int idx = base + t * 4 + i;
        vals[i] = (idx < n) ? deg[idx] : 0;
        s += vals[i];
    }
    sh[t] = s;
    __syncthreads();
    for (int off = 1; off < SC_T; off <<= 1) {
        int v = (t >= off) ? sh[t - off] : 0;
        __syncthreads();
        sh[t] += v;
        __syncthreads();
    }
    int excl = sh[t] - s + bsum[blockIdx.x];
    for (int i = 0; i < 4; i++) {
        int idx = base + t * 4 + i;
        if (idx < n) { rp[idx] = excl; excl += vals[i]; }
    }
    if (blockIdx.x == 0 && t == 0) rp[n] = *total;
}

// ================= W1 pre-pack into MFMA B-fragment layout =================

__global__ void pack_w(const float* __restrict__ W, ushort* __restrict__ Wp) {
    int kc = blockIdx.x >> 3, n = blockIdx.x & 7;
    int l = threadIdx.x;
    ushort o[8];
#pragma unroll
    for (int j = 0; j < 8; ++j) {
        float v = W[(size_t)(kc * 32 + ((l >> 4) * 8) + j) * 128 + n * 16 + (l & 15)];
        o[j] = f2bf(v);
    }
    uint4 pk;
    pk.x = (uint)o[0] | ((uint)o[1] << 16);
    pk.y = (uint)o[2] | ((uint)o[3] << 16);
    pk.z = (uint)o[4] | ((uint)o[5] << 16);
    pk.w = (uint)o[6] | ((uint)o[7] << 16);
    *(uint4*)(Wp + ((size_t)(kc * 8 + n) * 64 + l) * 8) = pk;
}

// ================= GEMM1: Cb[M,128](bf16) = X[M,K](fp32) @ W1 (packed) =================

__global__ __launch_bounds__(256) void gemm1_mfma(
        const float* __restrict__ X, const ushort* __restrict__ Wp,
        ushort* __restrict__ Cb, int M, int K) {
    __shared__ ushort As[2][64][40];
    int t = threadIdx.x, lane = t & 63, w = t >> 6;
    int brow = blockIdx.x * 64;
    int KC = K >> 5;
    f32x4 acc[8] = {};
    int sr = t >> 2, sk = (t & 3) * 8;
    int gr = brow + sr;
    bool xok = gr < M;
    int frow = w * 16 + (lane & 15);
    int fk = (lane >> 4) * 8;

    auto loadpk = [&](int kc) -> uint4 {
        float4 xa = make_float4(0.f, 0.f, 0.f, 0.f), xb = xa;
        if (xok) {
            const float* xp = X + (size_t)gr * K + kc * 32 + sk;
            xa = *(const float4*)xp;
            xb = *(const float4*)(xp + 4);
        }
        uint4 pk;
        pk.x = pk2(xa.x, xa.y);
        pk.y = pk2(xa.z, xa.w);
        pk.z = pk2(xb.x, xb.y);
        pk.w = pk2(xb.z, xb.w);
        return pk;
    };

    uint4 cur = loadpk(0);
    int buf = 0;
    for (int kc = 0; kc < KC; ++kc) {
        *(uint4*)&As[buf][sr][sk] = cur;
        __syncthreads();
        if (kc + 1 < KC) cur = loadpk(kc + 1);
        bf16x8 af = *(const bf16x8*)&As[buf][frow][fk];
        const ushort* wbase = Wp + ((size_t)(kc * 8) * 64 + lane) * 8;
#pragma unroll
        for (int n = 0; n < 8; ++n) {
            bf16x8 bfr = *(const bf16x8*)(wbase + (size_t)n * 64 * 8);
            acc[n] = __builtin_amdgcn_mfma_f32_16x16x32_bf16(af, bfr, acc[n], 0, 0, 0);
        }
        buf ^= 1;
    }
    int colbase = lane & 15;
    int rowbase = brow + w * 16 + ((lane >> 4) << 2);
#pragma unroll
    for (int n = 0; n < 8; ++n) {
#pragma unroll
        for (int r = 0; r < 4; ++r) {
            int grr = rowbase + r;
            if (grr < M) Cb[(size_t)grr * 128 + n * 16 + colbase] = f2bf(acc[n][r]);
        }
    }
}

// ================= layer-1 prop, branch 0: B = relu(S*A + b1), fused weighted colsum =================

#define ACC8(acc, g, w)                                   \
    acc[0] += bflo(g.x) * w; acc[1] += bfhi(g.x) * w;     \
    acc[2] += bflo(g.y) * w; acc[3] += bfhi(g.y) * w;     \
    acc[4] += bflo(g.z) * w; acc[5] += bfhi(g.z) * w;     \
    acc[6] += bflo(g.w) * w; acc[7] += bfhi(g.w) * w;

__global__ __launch_bounds__(256) void prop_b0(
        const ushort* __restrict__ A,
        const int* __restrict__ rp, const int* __restrict__ adj,
        const float* __restrict__ dinv, const float* __restrict__ tv,
        const float* __restrict__ bias,
        ushort* __restrict__ B, float* __restrict__ mparts, int n) {
    __shared__ float msum[128];
    int t = threadIdx.x;
    if (t < 128) msum[t] = 0.f;
    __syncthreads();
    int wave = (blockIdx.x * blockDim.x + t) >> 6;
    int lane = t & 63;
    int q = lane >> 4, l = lane & 15;
    int v = wave * 4 + q;
    bool vok = v < n;
    int vc = vok ? v : (n - 1);
    float dv = dinv[vc];

    uint4 r0 = *(const uint4*)(A + (size_t)vc * 128 + 8 * l);
    float a0[8];
    a0[0] = bflo(r0.x) * dv; a0[1] = bfhi(r0.x) * dv;
    a0[2] = bflo(r0.y) * dv; a0[3] = bfhi(r0.y) * dv;
    a0[4] = bflo(r0.z) * dv; a0[5] = bfhi(r0.z) * dv;
    a0[6] = bflo(r0.w) * dv; a0[7] = bfhi(r0.w) * dv;

    int i = rp[vc], end = rp[vc + 1];
    int un[4];
#pragma unroll
    for (int k = 0; k < 4; ++k) un[k] = (i + k < end) ? adj[i + k] : vc;

    while (__ballot(i < end)) {
        int uc[4];
#pragma unroll
        for (int k = 0; k < 4; ++k) uc[k] = un[k];
        uint4 g0[4];
#pragma unroll
        for (int k = 0; k < 4; ++k) g0[k] = *(const uint4*)(A + (size_t)uc[k] * 128 + 8 * l);
        float du[4];
#pragma unroll
        for (int k = 0; k < 4; ++k) du[k] = (i + k < end) ? dinv[uc[k]] : 0.f;
        i += 4;
#pragma unroll
        for (int k = 0; k < 4; ++k) un[k] = (i + k < end) ? adj[i + k] : vc;
#pragma unroll
        for (int k = 0; k < 4; ++k) {
            float w = du[k];
            ACC8(a0, g0[k], w)
        }
    }
    float4 bA = *(const float4*)(bias + 8 * l);
    float4 bB = *(const float4*)(bias + 8 * l + 4);
    float bb[8] = {bA.x, bA.y, bA.z, bA.w, bB.x, bB.y, bB.z, bB.w};
#pragma unroll
    for (int j = 0; j < 8; ++j)
        a0[j] = fmaxf(a0[j] * dv + bb[j], 0.f);
    if (vok) {
        uint4 o;
        o.x = pk2(a0[0], a0[1]); o.y = pk2(a0[2], a0[3]);
        o.z = pk2(a0[4], a0[5]); o.w = pk2(a0[6], a0[7]);
        *(uint4*)(B + (size_t)v * 128 + 8 * l) = o;
    }
    float tvv = vok ? tv[vc] : 0.f;
#pragma unroll
    for (int j = 0; j < 8; ++j)
        atomicAdd(&msum[8 * l + j], tvv * a0[j]);
    __syncthreads();
    if (t < 128)
        atomicAdd(&mparts[(size_t)(blockIdx.x & 31) * 128 + t], msum[t]);
}

// ================= branch 1 + fused dots =================

__global__ __launch_bounds__(256) void prop_b1(
        const ushort* __restrict__ A, const ushort* __restrict__ B,
        const int* __restrict__ rp, const int* __restrict__ adj,
        const float* __restrict__ dinv, const int* __restrict__ perm,
        const float* __restrict__ bias, const float* __restrict__ w2s,
        float2* __restrict__ cpair, int n) {
    int wave = (blockIdx.x * blockDim.x + threadIdx.x) >> 6;
    int lane = threadIdx.x & 63;
    int q = lane >> 4, l = lane & 15;
    int v = wave * 4 + q;
    bool vok = v < n;
    int vc = vok ? v : (n - 1);
    float dv = dinv[vc];
    int self = perm[vc];

    uint4 r1 = *(const uint4*)(A + (size_t)self * 128 + 8 * l);
    float a1[8];
    a1[0] = bflo(r1.x) * dv; a1[1] = bfhi(r1.x) * dv;
    a1[2] = bflo(r1.y) * dv; a1[3] = bfhi(r1.y) * dv;
    a1[4] = bflo(r1.z) * dv; a1[5] = bfhi(r1.z) * dv;
    a1[6] = bflo(r1.w) * dv; a1[7] = bfhi(r1.w) * dv;

    int i = rp[vc], end = rp[vc + 1];
    int un[4];
#pragma unroll
    for (int k = 0; k < 4; ++k) un[k] = (i + k < end) ? adj[i + k] : vc;

    while (__ballot(i < end)) {
        int uc[4];
#pragma unroll
        for (int k = 0; k < 4; ++k) uc[k] = un[k];
        int uu[4];
#pragma unroll
        for (int k = 0; k < 4; ++k) uu[k] = perm[uc[k]];
        uint4 g1[4];
#pragma unroll
        for (int k = 0; k < 4; ++k) g1[k] = *(const uint4*)(A + (size_t)uu[k] * 128 + 8 * l);
        float du[4];
#pragma unroll
        for (int k = 0; k < 4; ++k) du[k] = (i + k < end) ? dinv[uc[k]] : 0.f;
        i += 4;
#pragma unroll
        for (int k = 0; k < 4; ++k) un[k] = (i + k < end) ? adj[i + k] : vc;
#pragma unroll
        for (int k = 0; k < 4; ++k) {
            float w = du[k];
            ACC8(a1, g1[k], w)
        }
    }
    if (!vok) return;
    float4 bA = *(const float4*)(bias + 8 * l);
    float4 bB = *(const float4*)(bias + 8 * l + 4);
    float bb[8] = {bA.x, bA.y, bA.z, bA.w, bB.x, bB.y, bB.z, bB.w};
    float4 wA = *(const float4*)(w2s + 8 * l);
    float4 wB = *(const float4*)(w2s + 8 * l + 4);
    float ww[8] = {wA.x, wA.y, wA.z, wA.w, wB.x, wB.y, wB.z, wB.w};
    float c1 = 0.f;
#pragma unroll
    for (int j = 0; j < 8; ++j)
        c1 += fmaxf(a1[j] * dv + bb[j], 0.f) * ww[j];
    uint4 b0 = *(const uint4*)(B + (size_t)vc * 128 + 8 * l);
    float c0 = bflo(b0.x) * ww[0] + bfhi(b0.x) * ww[1]
             + bflo(b0.y) * ww[2] + bfhi(b0.y) * ww[3]
             + bflo(b0.z) * ww[4] + bfhi(b0.z) * ww[5]
             + bflo(b0.w) * ww[6] + bfhi(b0.w) * ww[7];
#pragma unroll
    for (int off = 1; off < 16; off <<= 1) {
        c0 += __shfl_xor(c0, off);
        c1 += __shfl_xor(c1, off);
    }
    if (l == 0) cpair[v] = make_float2(dv * c0, dv * c1);
}

// ================= readout =================

__global__ void tiny_chain(const float* __restrict__ mparts, const float* __restrict__ W2,
                           const float* __restrict__ b2, const float* __restrict__ Wd,
                           const float* __restrict__ bd,
                           float* __restrict__ w2s, float* __restrict__ k0, int n) {
    __shared__ float mB[128];
    __shared__ float s_sh[128];
    __shared__ float ws_sh[128];
    __shared__ float red[128];
    int t = threadIdx.x;
    float acc = 0.f;
    for (int r = 0; r < 32; ++r) acc += mparts[(size_t)r * 128 + t];
    mB[t] = acc;
    __syncthreads();
    acc = 0.f;
    for (int k = 0; k < 128; ++k) acc += mB[k] * W2[k * 128 + t];
    float m = acc / (float)n + b2[t];
    s_sh[t] = 1.f / (1.f + expf(-m));
    __syncthreads();
    acc = 0.f;
    for (int j = 0; j < 128; ++j) acc += Wd[t * 128 + j] * s_sh[j];
    ws_sh[t] = acc;
    __syncthreads();
    acc = 0.f;
    for (int j = 0; j < 128; ++j) acc += W2[t * 128 + j] * ws_sh[j];
    w2s[t] = acc;
    red[t] = b2[t] * ws_sh[t];
    __syncthreads();
    for (int off = 64; off > 0; off >>= 1) {
        if (t < off) red[t] += red[t + off];
        __syncthreads();
    }
    if (t == 0) *k0 = red[0] + bd[0];
}

__global__ __launch_bounds__(256) void sprop(
        const float2* __restrict__ cpair,
        const int* __restrict__ rp, const int* __restrict__ adj,
        const float* __restrict__ dinv, const float* __restrict__ k0,
        float* __restrict__ out, int n) {
    int wave = (blockIdx.x * blockDim.x + threadIdx.x) >> 6;
    int lane = threadIdx.x & 63;
    int q = lane >> 4, l = lane & 15;
    int v = wave * 4 + q;
    if (v >= n) return;
    float a0 = 0.f, a1 = 0.f;
    int beg = rp[v], end = rp[v + 1];
    for (int i = beg + l; i < end; i += 16) {
        float2 c = cpair[adj[i]];
        a0 += c.x;
        a1 += c.y;
    }
#pragma unroll
    for (int off = 1; off < 16; off <<= 1) {
        a0 += __shfl_xor(a0, off);
        a1 += __shfl_xor(a1, off);
    }
    if (l == 0) {
        float dv = dinv[v];
        float kk = *k0;
        float2 cs = cpair[v];
        out[v] = dv * (a0 + cs.x) + kk;
        out[n + v] = dv * (a1 + cs.y) + kk;
    }
}

// ================= launch =================

extern "C" void kernel_launch(void* const* d_in, const int* in_sizes, int n_in,
                              void* d_out, int out_size, void* d_ws, size_t ws_size,
                              hipStream_t stream) {
    const float* x  = (const float*)d_in[0];
    const int*   ei = (const int*)d_in[1];
    const int* perm = (const int*)d_in[2];
    const float* W1 = (const float*)d_in[3];
    const float* b1 = (const float*)d_in[4];
    const float* W2 = (const float*)d_in[5];
    const float* b2 = (const float*)d_in[6];
    const float* Wd = (const float*)d_in[7];
    const float* bd = (const float*)d_in[8];

    const int N = in_sizes[2];
    const int E = in_sizes[1] / 2;
    const int IN = in_sizes[0] / N;  // 512
    const int* src = ei;
    const int* dst = ei + E;
    float* out = (float*)d_out;

    const int NB = (N + 255) >> 8;          // <= 512
    const int M2 = 2 * NB * CS_G;           // dual counts array size
    int chunk = (E + CS_G - 1) / CS_G;
    chunk = (chunk + 3) & ~3;               // multiple of 4 for int4 loads

    char* p = (char*)d_ws;
    auto alloc = [&](size_t bytes) -> void* {
        void* r = (void*)p;
        p += (bytes + 511) & ~(size_t)511;
        return r;
    };
    float* mparts = (float*)alloc(32 * 128 * 4);   // zeroed each call
    uint*  counts = (uint*)alloc((size_t)M2 * 4);
    uint*  scn    = (uint*)alloc((size_t)(M2 + 1) * 4);
    uint*  rec    = (uint*)alloc((size_t)2 * E * 4);
    int*   rp     = (int*)alloc((size_t)(N + 1) * 4);
    int*   adj    = (int*)alloc((size_t)E * 4);
    float* dinv   = (float*)alloc((size_t)N * 4);
    float* tvv    = (float*)alloc((size_t)N * 4);
    int*   bsum   = (int*)alloc(4096);
    int*   total  = (int*)alloc(64);
    float* w2sv   = (float*)alloc(512);
    float* k0v    = (float*)alloc(64);
    float2* cpair = (float2*)alloc((size_t)N * 8);
    ushort* W1p   = (ushort*)alloc((size_t)512 * 128 * 2);
    ushort* A  = (ushort*)alloc((size_t)N * 128 * 2);
    ushort* B  = (ushort*)alloc((size_t)N * 128 * 2);

    hipMemsetAsync(mparts, 0, 32 * 128 * 4, stream);

    // --- fused dual counting sort ---
    part_hist_dual<<<CS_G, 256, 0, stream>>>(src, dst, counts, E, NB, chunk);
    int nb_sc = (M2 + SC_C - 1) / SC_C;     // <= 1024
    scan_part<<<nb_sc, SC_T, 0, stream>>>((const int*)counts, bsum, M2);
    scan_block<<<1, 256, 0, stream>>>(bsum, nb_sc, total);
    scan_write<<<nb_sc, SC_T, 0, stream>>>((const int*)counts, bsum, total, (int*)scn, M2);
    part_scatter_dual<<<CS_G, 256, 0, stream>>>(src, dst, scn, rec, E, NB, chunk);
    bucket_build<<<NB, 256, 0, stream>>>(scn, rec, rp, adj, dinv, NB, N);
    bucket_tw<<<NB, 256, 0, stream>>>(scn, rec, dinv, tvv, NB, N);

    // --- dense pipeline ---
    pack_w<<<(IN / 32) * 8, 64, 0, stream>>>(W1, W1p);

    int gemm_blocks = (N + 63) / 64;
    int p4_blocks = ((N + 3) / 4 + 3) / 4;

    gemm1_mfma<<<gemm_blocks, 256, 0, stream>>>(x, W1p, A, N, IN);
    prop_b0<<<p4_blocks, 256, 0, stream>>>(A, rp, adj, dinv, tvv, b1, B, mparts, N);
    tiny_chain<<<1, 128, 0, stream>>>(mparts, W2, b2, Wd, bd, w2sv, k0v, N);
    prop_b1<<<p4_blocks, 256, 0, stream>>>(A, B, rp, adj, dinv, perm, b1, w2sv, cpair, N);
    sprop<<<p4_blocks, 256, 0, stream>>>(cpair, rp, adj, dinv, k0v, out, N);
}